// Round 9
// baseline (494.184 us; speedup 1.0000x reference)
//
#include <hip/hip_runtime.h>
#include <hip/hip_cooperative_groups.h>
#include <math.h>

namespace cg = cooperative_groups;

#define Bsz 4
#define Nseq 2048
#define Cdim 512
#define Hn 8
#define Dh 64
#define TK 256
#define BH (Bsz*Hn)          // 32
#define QKVC 1536

typedef __attribute__((ext_vector_type(8))) short bf16x8;
typedef __attribute__((ext_vector_type(4))) float f32x4;

__device__ __forceinline__ unsigned short f2bf(float x) {
    unsigned u = __float_as_uint(x);
    unsigned r = (u + 0x7fffu + ((u >> 16) & 1u)) >> 16;   // round-to-nearest-even
    return (unsigned short)r;
}
__device__ __forceinline__ float bf2f(unsigned short h) {
    return __uint_as_float((unsigned)h << 16);
}
__device__ __forceinline__ f32x4 mfma16(bf16x8 a, bf16x8 b, f32x4 c) {
    return __builtin_amdgcn_mfma_f32_16x16x32_bf16(a, b, c, 0, 0, 0);
}

// ---------------- shared-memory stage structs ----------------
struct S2Sh { float xr[8][32]; float xs[32]; };
struct S3Sh { float qm[64]; float km[64]; };
struct S4Sh { float vs[8 * 8 * 68]; };
struct S5Sh { int hist[256]; int sS[256]; int tieidx[2048]; int D; int above; int tiecnt; };
struct S7Sh { float Kt[64 * 256]; float Qs[16 * 64]; float umS[16]; float izS[16]; };
struct S8Sh { float As[64][65]; float Ws[64][132]; float red[4][64]; };
union FusedSh {
    S2Sh s2; S3Sh s3; S4Sh s4; S5Sh s5; S7Sh s7; S8Sh s8;
};

// =================================================================
// Stage bodies (identical math to round 8), unit index u = old blockIdx
// =================================================================

// ---- S1 prep: u in [0,896) ----
__device__ void prep_body(int u, const float* __restrict__ w_qkv,
                          bf16x8* __restrict__ hi, bf16x8* __restrict__ lo,
                          const float* __restrict__ x, float* __restrict__ xpart) {
    int tid = threadIdx.x;
    if (u < 384) {
        int nt = u >> 2;
        int kt = (u & 3) * 4 + (tid >> 6);
        int lane = tid & 63;
        int c = nt * 16 + (lane & 15);
        int kbase = kt * 32 + (lane >> 4) * 8;
        bf16x8 h, l;
        #pragma unroll
        for (int j = 0; j < 8; ++j) {
            float v = w_qkv[(size_t)(kbase + j) * QKVC + c];
            unsigned short hv = f2bf(v);
            h[j] = (short)hv;
            l[j] = (short)f2bf(v - bf2f(hv));
        }
        int idx = (nt * 16 + kt) * 64 + lane;
        hi[idx] = h;
        lo[idx] = l;
    } else {
        int r = u - 384;
        int b = r >> 7, rc = r & 127;
        const float* xp = x + ((size_t)b * Nseq + rc * 16) * Cdim;
        float s0 = 0.f, s1 = 0.f;
        #pragma unroll 4
        for (int rr = 0; rr < 16; ++rr) {
            s0 += xp[rr * Cdim + tid];
            s1 += xp[rr * Cdim + 256 + tid];
        }
        xpart[((size_t)b * 128 + rc) * Cdim + tid] = s0;
        xpart[((size_t)b * 128 + rc) * Cdim + 256 + tid] = s1;
    }
}

// ---- S2 statsA: u in [0,384): b=u&3, kc=(u>>2)&15, nb=u>>6 ----
__device__ void statsA_body(int u, const float* __restrict__ xpart,
                            const float* __restrict__ w_qkv,
                            float* __restrict__ spart, S2Sh& s) {
    int b = u & 3, kc = (u >> 2) & 15, nb = u >> 6;
    int t = threadIdx.x;
    int i = t & 31, g = t >> 5;
    float acc = 0.f;
    #pragma unroll 4
    for (int j = 0; j < 16; ++j)
        acc += xpart[((size_t)b * 128 + g * 16 + j) * Cdim + kc * 32 + i];
    s.xr[g][i] = acc;
    __syncthreads();
    if (t < 32) {
        float v = 0.f;
        #pragma unroll
        for (int gg = 0; gg < 8; ++gg) v += s.xr[gg][t];
        s.xs[t] = v;
    }
    __syncthreads();
    float a0 = 0.f;
    const float* wbase = w_qkv + (size_t)(kc * 32) * QKVC + nb * 256 + t;
    #pragma unroll 4
    for (int i2 = 0; i2 < 32; ++i2)
        a0 += s.xs[i2] * wbase[(size_t)i2 * QKVC];
    spart[(size_t)(b * 16 + kc) * QKVC + nb * 256 + t] = a0;
}

// ---- S3 statsB: u in [0,64): bh=u&31, cb=u>>5 ----
__device__ void statsB_body(int u, const float* __restrict__ spart,
                            const float* __restrict__ w_qkv,
                            float* __restrict__ sv, float* __restrict__ rvec,
                            float* __restrict__ cvec, S3Sh& s) {
    int bh = u & 31, cb = u >> 5;
    int b = bh >> 3, h = bh & 7;
    int t = threadIdx.x;
    if (t < 192) {
        int which = t >> 6, d = t & 63;
        int col = which * 512 + h * 64 + d;
        float sm = 0.f;
        #pragma unroll
        for (int kc = 0; kc < 16; ++kc)
            sm += spart[(size_t)(b * 16 + kc) * QKVC + col];
        if (which == 0)      s.qm[d] = sm * (1.0f / Nseq);
        else if (which == 1) s.km[d] = sm * (1.0f / Nseq);
        else if (cb == 0)    sv[bh * 64 + d] = sm;
    }
    __syncthreads();
    int c = cb * 256 + t;
    const float4* wr = (const float4*)(w_qkv + (size_t)c * QKVC + h * 64);
    const float4* wc = (const float4*)(w_qkv + (size_t)c * QKVC + 512 + h * 64);
    float r = 0.f, cv = 0.f;
    #pragma unroll
    for (int d4 = 0; d4 < 16; ++d4) {
        float4 w1 = wr[d4], w2 = wc[d4];
        float4 k1 = *(const float4*)&s.km[d4 * 4];
        float4 q1 = *(const float4*)&s.qm[d4 * 4];
        r  += w1.x * k1.x + w1.y * k1.y + w1.z * k1.z + w1.w * k1.w;
        cv += w2.x * q1.x + w2.y * q1.y + w2.z * q1.z + w2.w * q1.w;
    }
    rvec[(size_t)bh * Cdim + c] = r;
    cvec[(size_t)bh * Cdim + c] = cv;
}

// ---- S4 score3: u in [0,512): b=u&3, rc=(u>>2)&63, half=u>>8 ----
__device__ void score3_body(int u, const float* __restrict__ x,
                            const float* __restrict__ rvec,
                            const float* __restrict__ cvec,
                            float* __restrict__ rsc, float* __restrict__ csc,
                            S4Sh& s) {
    int b = u & 3, rc = (u >> 2) & 63, half = u >> 8;
    int t = threadIdx.x;
    int r = t >> 3, g = t & 7;
    const float4* xp = (const float4*)(x + ((size_t)b * Nseq + rc * 32 + r) * Cdim + g * 64);
    float4 xr[16];
    #pragma unroll
    for (int j4 = 0; j4 < 16; ++j4) xr[j4] = xp[j4];
    {
        const float* src = half ? cvec : rvec;
        const float4* sp = (const float4*)(src + (size_t)b * 8 * Cdim);
        for (int i = t; i < 8 * 128; i += 256) {
            int v = i >> 7, c4 = i & 127;
            float4 val = sp[v * 128 + c4];
            int gg = c4 >> 4, j4 = c4 & 15;
            *(float4*)&s.vs[(v * 8 + gg) * 68 + j4 * 4] = val;
        }
    }
    __syncthreads();
    float acc[8];
    #pragma unroll
    for (int v = 0; v < 8; ++v) acc[v] = 0.f;
    #pragma unroll
    for (int j4 = 0; j4 < 16; ++j4) {
        float4 xv = xr[j4];
        #pragma unroll
        for (int v = 0; v < 8; ++v) {
            float4 wv = *(const float4*)&s.vs[(v * 8 + g) * 68 + j4 * 4];
            acc[v] += xv.x * wv.x + xv.y * wv.y + xv.z * wv.z + xv.w * wv.w;
        }
    }
    #pragma unroll
    for (int v = 0; v < 8; ++v) {
        float sm = acc[v];
        sm += __shfl_xor(sm, 1, 64);
        sm += __shfl_xor(sm, 2, 64);
        sm += __shfl_xor(sm, 4, 64);
        acc[v] = sm;
    }
    if (g == 0) {
        int i = rc * 32 + r;
        float* outp = half ? csc : rsc;
        #pragma unroll
        for (int v = 0; v < 8; ++v)
            outp[(size_t)(b * 8 + v) * Nseq + i] = acc[v] * 0.125f;
    }
}

// ---- S5 topk4: u in [0,64) ----
__device__ void topk4_body(int u, const float* __restrict__ rsc,
                           const float* __restrict__ csc,
                           int* __restrict__ ridx, int* __restrict__ cidx,
                           int* __restrict__ rankmap, S5Sh& s) {
    int bh = u >> 1, which = u & 1;
    const float* sin = which ? (csc + (size_t)bh * Nseq) : (rsc + (size_t)bh * Nseq);
    int tid = threadIdx.x;
    unsigned k[8];
    #pragma unroll
    for (int j = 0; j < 8; ++j) {
        unsigned uu = __float_as_uint(sin[j * 256 + tid]);
        k[j] = (uu & 0x80000000u) ? ~uu : (uu | 0x80000000u);
    }
    unsigned pref = 0;
    int above = 0;
    for (int level = 3; level >= 0; --level) {
        s.hist[tid] = 0;
        __syncthreads();
        int sh = level * 8;
        #pragma unroll
        for (int j = 0; j < 8; ++j) {
            bool match;
            if (level == 3) match = true;
            else            match = ((k[j] >> (sh + 8)) == pref);
            if (match) atomicAdd(&s.hist[(k[j] >> sh) & 255], 1);
        }
        __syncthreads();
        s.sS[tid] = s.hist[tid];
        __syncthreads();
        for (int off = 1; off < 256; off <<= 1) {
            int v = (tid + off < 256) ? s.sS[tid + off] : 0;
            __syncthreads();
            s.sS[tid] += v;
            __syncthreads();
        }
        int Sincl = s.sS[tid];
        int Sexcl = (tid < 255) ? s.sS[tid + 1] : 0;
        if (above + Sexcl < TK && above + Sincl >= TK) {
            s.D = tid;
            s.above = above + Sexcl;
        }
        __syncthreads();
        pref = (pref << 8) | (unsigned)s.D;
        above = s.above;
        __syncthreads();
    }
    unsigned T = pref;
    int rem = TK - above;
    if (tid == 0) s.tiecnt = 0;
    __syncthreads();
    int cnt = 0;
    #pragma unroll
    for (int j = 0; j < 8; ++j) {
        if (k[j] > T) ++cnt;
        if (k[j] == T) {
            int p = atomicAdd(&s.tiecnt, 1);
            s.tieidx[p] = j * 256 + tid;
        }
    }
    s.sS[tid] = cnt;
    __syncthreads();
    for (int off = 1; off < 256; off <<= 1) {
        int v = (tid >= off) ? s.sS[tid - off] : 0;
        __syncthreads();
        s.sS[tid] += v;
        __syncthreads();
    }
    int base = s.sS[tid] - cnt;
    int tc = s.tiecnt;
    int* outp = which ? (cidx + bh * TK) : (ridx + bh * TK);
    #pragma unroll
    for (int j = 0; j < 8; ++j) {
        int i = j * 256 + tid;
        int r = -1;
        if (k[j] > T) {
            r = base++;
        } else if (k[j] == T) {
            int rk = 0;
            for (int t2 = 0; t2 < tc; ++t2) rk += (s.tieidx[t2] < i) ? 1 : 0;
            if (rk < rem) r = above + rk;
        }
        if (r >= 0) outp[r] = i;
        if (which == 0) rankmap[(size_t)bh * Nseq + i] = r;
    }
}

// ---- S6 selgemm3: u in [0,384): mq=u&3, part=(u>>2)%3, bh=(u>>2)/3 ----
__device__ void selgemm3_body(int u, const float* __restrict__ x,
                              const int* __restrict__ ridx,
                              const int* __restrict__ cidx,
                              const bf16x8* __restrict__ Bph,
                              const bf16x8* __restrict__ Bpl,
                              float* __restrict__ qsel,
                              float* __restrict__ ksel,
                              float* __restrict__ vsel) {
    int mq = u & 3, part = (u >> 2) % 3, bh = (u >> 2) / 3;
    int b = bh >> 3, h = bh & 7;
    int tid = threadIdx.x;
    int wv = tid >> 6, lane = tid & 63;
    const int* idxp = (part == 0 ? ridx : cidx) + bh * TK + mq * 64 + wv * 16;
    int row = idxp[lane & 15];
    const float* ap = x + ((size_t)b * Nseq + row) * Cdim + (lane >> 4) * 8;
    size_t orow = (size_t)bh * TK + mq * 64 + wv * 16;
    int nt0 = (part == 0) ? (h * 4) : (part == 1 ? (32 + h * 4) : (64 + h * 4));
    float* outp = (part == 0) ? qsel : (part == 1 ? ksel : vsel);

    f32x4 acc[4];
    #pragma unroll
    for (int i = 0; i < 4; ++i) acc[i] = (f32x4){0.f, 0.f, 0.f, 0.f};
    float4 a0 = *(const float4*)ap;
    float4 a1 = *(const float4*)(ap + 4);
    #pragma unroll 2
    for (int kt = 0; kt < 16; ++kt) {
        float4 na0 = a0, na1 = a1;
        if (kt < 15) {
            na0 = *(const float4*)(ap + (kt + 1) * 32);
            na1 = *(const float4*)(ap + (kt + 1) * 32 + 4);
        }
        float vv[8] = {a0.x, a0.y, a0.z, a0.w, a1.x, a1.y, a1.z, a1.w};
        bf16x8 ah, al;
        #pragma unroll
        for (int j = 0; j < 8; ++j) {
            unsigned short hv = f2bf(vv[j]);
            ah[j] = (short)hv;
            al[j] = (short)f2bf(vv[j] - bf2f(hv));
        }
        #pragma unroll
        for (int ni = 0; ni < 4; ++ni) {
            int nt16 = nt0 + ni;
            bf16x8 bh8 = Bph[((size_t)nt16 * 16 + kt) * 64 + lane];
            bf16x8 bl8 = Bpl[((size_t)nt16 * 16 + kt) * 64 + lane];
            acc[ni] = mfma16(ah, bh8, acc[ni]);
            acc[ni] = mfma16(ah, bl8, acc[ni]);
            acc[ni] = mfma16(al, bh8, acc[ni]);
        }
        a0 = na0; a1 = na1;
    }
    int cl = lane & 15, rq = (lane >> 4) * 4;
    #pragma unroll
    for (int ni = 0; ni < 4; ++ni) {
        int csub = ni * 16 + cl;
        #pragma unroll
        for (int r = 0; r < 4; ++r)
            outp[(orow + rq + r) * 64 + csub] = acc[ni][r];
    }
}

// ---- S7 attn: u in [0,512): bh=u&31, rblk=u>>5 ----
__device__ void attn_body(int u, const float* __restrict__ qsel,
                          const float* __restrict__ ksel,
                          const float* __restrict__ vsel,
                          const float* __restrict__ sv,
                          float* __restrict__ delta, S7Sh& s) {
    int bh = u & 31, rblk = u >> 5;
    int tid = threadIdx.x;
    {
        int j = tid;
        const float4* kp4 = (const float4*)(ksel + ((size_t)bh * TK + j) * 64);
        #pragma unroll
        for (int d4 = 0; d4 < 16; ++d4) {
            float4 kv = kp4[d4];
            s.Kt[(d4 * 4 + 0) * 256 + j] = kv.x;
            s.Kt[(d4 * 4 + 1) * 256 + j] = kv.y;
            s.Kt[(d4 * 4 + 2) * 256 + j] = kv.z;
            s.Kt[(d4 * 4 + 3) * 256 + j] = kv.w;
        }
    }
    for (int idx = tid; idx < 16 * 64; idx += 256)
        s.Qs[idx] = qsel[((size_t)bh * TK + rblk * 16) * 64 + idx];
    __syncthreads();

    int wave = tid >> 6, lane = tid & 63;
    int iw0 = wave * 4;
    float e[4][4];
    #pragma unroll
    for (int r = 0; r < 4; ++r)
        #pragma unroll
        for (int t = 0; t < 4; ++t) e[r][t] = 0.f;
    #pragma unroll 8
    for (int d = 0; d < 64; ++d) {
        float4 kv = *(const float4*)&s.Kt[d * 256 + 4 * lane];
        #pragma unroll
        for (int r = 0; r < 4; ++r) {
            float qd = s.Qs[(iw0 + r) * 64 + d];
            e[r][0] += qd * kv.x; e[r][1] += qd * kv.y;
            e[r][2] += qd * kv.z; e[r][3] += qd * kv.w;
        }
    }
    #pragma unroll
    for (int r = 0; r < 4; ++r) {
        float s0 = e[r][0] * 0.125f, s1 = e[r][1] * 0.125f;
        float s2 = e[r][2] * 0.125f, s3 = e[r][3] * 0.125f;
        float mx = fmaxf(fmaxf(s0, s1), fmaxf(s2, s3));
        #pragma unroll
        for (int off = 32; off; off >>= 1) mx = fmaxf(mx, __shfl_xor(mx, off, 64));
        mx = fmaxf(mx, 0.0f);
        float e0 = __expf(s0 - mx), e1 = __expf(s1 - mx);
        float e2 = __expf(s2 - mx), e3 = __expf(s3 - mx);
        float zs = e0 + e1 + e2 + e3;
        #pragma unroll
        for (int off = 32; off; off >>= 1) zs += __shfl_xor(zs, off, 64);
        if (lane == 0) {
            float em = __expf(-mx);
            s.umS[iw0 + r] = em;
            s.izS[iw0 + r] = 1.0f / ((float)(Nseq - TK) * em + zs);
        }
        e[r][0] = e0; e[r][1] = e1; e[r][2] = e2; e[r][3] = e3;
    }
    __syncthreads();
    float* E = s.Kt;
    #pragma unroll
    for (int r = 0; r < 4; ++r)
        *(float4*)&E[(iw0 + r) * 256 + 4 * lane] = (float4){e[r][0], e[r][1], e[r][2], e[r][3]};
    __syncthreads();

    const float* vbase = vsel + (size_t)bh * TK * 64 + lane;
    float ssel = 0.f;
    float acc[4];
    #pragma unroll
    for (int r = 0; r < 4; ++r) acc[r] = 0.f;
    #pragma unroll 4
    for (int j = 0; j < TK; ++j) {
        float v = vbase[j * 64];
        ssel += v;
        #pragma unroll
        for (int r = 0; r < 4; ++r)
            acc[r] += E[(iw0 + r) * 256 + j] * v;
    }
    float svd = sv[bh * 64 + lane];
    float sadj = svd - ssel;
    float uval = svd * (1.0f / Nseq);
    #pragma unroll
    for (int r = 0; r < 4; ++r) {
        int i = rblk * 16 + iw0 + r;
        float outv = (s.umS[iw0 + r] * sadj + acc[r]) * s.izS[iw0 + r];
        delta[((size_t)bh * TK + i) * 64 + lane] = outv - uval;
    }
}

// ---- S8 deltamm_ub: u in [0,544) ----
__device__ void deltamm_body(int u, const float* __restrict__ delta,
                             const float* __restrict__ w_out,
                             const float* __restrict__ b_out,
                             const float* __restrict__ sv,
                             float* __restrict__ deltaout,
                             float* __restrict__ ubase, S8Sh& s) {
    int tid = threadIdx.x;
    if (u < 512) {
        int bh = u >> 4, sub = u & 15;
        int rh = sub >> 2, ct = sub & 3;
        int h = bh & 7;
        for (int idx = tid; idx < 64 * 64; idx += 256) {
            int row = idx >> 6, k = idx & 63;
            s.As[row][k] = delta[((size_t)bh * TK + rh * 64 + row) * 64 + k];
        }
        for (int idx = tid; idx < 64 * 128; idx += 256) {
            int k = idx >> 7, c = idx & 127;
            s.Ws[k][c] = w_out[(size_t)(h * 64 + k) * 512 + ct * 128 + c];
        }
        __syncthreads();
        int tx = tid & 15, ty = tid >> 4;
        float acc[4][8];
        #pragma unroll
        for (int r = 0; r < 4; ++r)
            #pragma unroll
            for (int c = 0; c < 8; ++c) acc[r][c] = 0.f;
        for (int k = 0; k < 64; ++k) {
            float a[4], bv[8];
            #pragma unroll
            for (int r = 0; r < 4; ++r) a[r] = s.As[ty * 4 + r][k];
            #pragma unroll
            for (int cc = 0; cc < 4; ++cc) {
                bv[cc]     = s.Ws[k][tx * 4 + cc];
                bv[4 + cc] = s.Ws[k][64 + tx * 4 + cc];
            }
            #pragma unroll
            for (int r = 0; r < 4; ++r)
                #pragma unroll
                for (int c = 0; c < 8; ++c) acc[r][c] += a[r] * bv[c];
        }
        #pragma unroll
        for (int r = 0; r < 4; ++r) {
            size_t ro = ((size_t)bh * TK + rh * 64 + ty * 4 + r) * 512 + ct * 128;
            #pragma unroll
            for (int cc = 0; cc < 4; ++cc) {
                deltaout[ro + tx * 4 + cc]      = acc[r][cc];
                deltaout[ro + 64 + tx * 4 + cc] = acc[r][4 + cc];
            }
        }
    } else {
        int r2 = u - 512;
        int b = r2 >> 3;
        int c0 = (r2 & 7) * 64;
        int c = tid & 63, kg = tid >> 6;
        float sm = 0.f;
        for (int k = kg * 128; k < kg * 128 + 128; ++k) {
            float hu = sv[(b * 8 + (k >> 6)) * 64 + (k & 63)] * (1.0f / Nseq);
            sm += hu * w_out[(size_t)k * 512 + c0 + c];
        }
        s.red[kg][c] = sm;
        __syncthreads();
        if (tid < 64)
            ubase[b * 512 + c0 + c] = s.red[0][c] + s.red[1][c] + s.red[2][c] + s.red[3][c] + b_out[c0 + c];
    }
}

// ---- S9 compose: u in [0,2048) ----
__device__ void compose_body(int u, const float* __restrict__ ubase,
                             const int* __restrict__ rankmap,
                             const float* __restrict__ deltaout,
                             float* __restrict__ out) {
    int r0 = u * 4;
    int b = r0 >> 11;
    int tid = threadIdx.x;
    float u0 = ubase[b * 512 + tid];
    float u1 = ubase[b * 512 + 256 + tid];
    for (int rr = 0; rr < 4; ++rr) {
        int i = (r0 + rr) & 2047;
        float a0 = u0, a1 = u1;
        #pragma unroll
        for (int h = 0; h < 8; ++h) {
            int rk = rankmap[(size_t)(b * 8 + h) * Nseq + i];
            if (rk >= 0) {
                const float* dp = deltaout + ((size_t)(b * 8 + h) * TK + rk) * 512;
                a0 += dp[tid];
                a1 += dp[256 + tid];
            }
        }
        float* op = out + ((size_t)b * Nseq + i) * 512;
        op[tid] = a0;
        op[256 + tid] = a1;
    }
}

// =================================================================
// Standalone kernels (fallback path, identical to round 8 behavior)
// =================================================================
__global__ __launch_bounds__(256) void prep_k(const float* w_qkv, bf16x8* hi, bf16x8* lo,
                                              const float* x, float* xpart) {
    prep_body(blockIdx.x, w_qkv, hi, lo, x, xpart);
}
__global__ __launch_bounds__(256) void statsA_k(const float* xpart, const float* w_qkv, float* spart) {
    __shared__ S2Sh s;
    statsA_body(blockIdx.x, xpart, w_qkv, spart, s);
}
__global__ __launch_bounds__(256) void statsB_k(const float* spart, const float* w_qkv,
                                                float* sv, float* rvec, float* cvec) {
    __shared__ S3Sh s;
    statsB_body(blockIdx.x, spart, w_qkv, sv, rvec, cvec, s);
}
__global__ __launch_bounds__(256) void score3_k(const float* x, const float* rvec, const float* cvec,
                                                float* rsc, float* csc) {
    __shared__ S4Sh s;
    score3_body(blockIdx.x, x, rvec, cvec, rsc, csc, s);
}
__global__ __launch_bounds__(256) void topk4_k(const float* rsc, const float* csc,
                                               int* ridx, int* cidx, int* rankmap) {
    __shared__ S5Sh s;
    topk4_body(blockIdx.x, rsc, csc, ridx, cidx, rankmap, s);
}
__global__ __launch_bounds__(256) void selgemm3_k(const float* x, const int* ridx, const int* cidx,
                                                  const bf16x8* Bph, const bf16x8* Bpl,
                                                  float* qsel, float* ksel, float* vsel) {
    selgemm3_body(blockIdx.x, x, ridx, cidx, Bph, Bpl, qsel, ksel, vsel);
}
__global__ __launch_bounds__(256) void attn_k(const float* qsel, const float* ksel, const float* vsel,
                                              const float* sv, float* delta) {
    __shared__ S7Sh s;
    attn_body(blockIdx.x, qsel, ksel, vsel, sv, delta, s);
}
__global__ __launch_bounds__(256) void deltamm_k(const float* delta, const float* w_out,
                                                 const float* b_out, const float* sv,
                                                 float* deltaout, float* ubase) {
    __shared__ S8Sh s;
    deltamm_body(blockIdx.x, delta, w_out, b_out, sv, deltaout, ubase, s);
}
__global__ __launch_bounds__(256) void compose_k(const float* ubase, const int* rankmap,
                                                 const float* deltaout, float* out) {
    compose_body(blockIdx.x, ubase, rankmap, deltaout, out);
}

// =================================================================
// fused_all: single cooperative kernel, 9 stages, 8 grid syncs.
// =================================================================
struct Params {
    const float* x; const float* w_qkv; const float* w_out; const float* b_out;
    float* out;
    float* xpart; float* spart; float* sv; float* rvec; float* cvec;
    float* rsc; float* csc; int* ridx; int* cidx; int* rankmap; float* ubase;
    const bf16x8* Bph; const bf16x8* Bpl;
    bf16x8* BphW; bf16x8* BplW;
    float* qsel; float* ksel; float* vsel; float* delta; float* deltaout;
};

__global__ __launch_bounds__(256, 2) void fused_all(Params p) {
    cg::grid_group grid = cg::this_grid();
    __shared__ FusedSh sh;
    int nb = gridDim.x;
    // S1 prep
    for (int u = blockIdx.x; u < 896; u += nb)
        prep_body(u, p.w_qkv, p.BphW, p.BplW, p.x, p.xpart);
    grid.sync();
    // S2 statsA
    for (int u = blockIdx.x; u < 384; u += nb) {
        statsA_body(u, p.xpart, p.w_qkv, p.spart, sh.s2);
        __syncthreads();
    }
    grid.sync();
    // S3 statsB
    for (int u = blockIdx.x; u < 64; u += nb) {
        statsB_body(u, p.spart, p.w_qkv, p.sv, p.rvec, p.cvec, sh.s3);
        __syncthreads();
    }
    grid.sync();
    // S4 score3
    for (int u = blockIdx.x; u < 512; u += nb) {
        score3_body(u, p.x, p.rvec, p.cvec, p.rsc, p.csc, sh.s4);
        __syncthreads();
    }
    grid.sync();
    // S5 topk4
    for (int u = blockIdx.x; u < 64; u += nb) {
        topk4_body(u, p.rsc, p.csc, p.ridx, p.cidx, p.rankmap, sh.s5);
        __syncthreads();
    }
    grid.sync();
    // S6 selgemm3
    for (int u = blockIdx.x; u < 384; u += nb)
        selgemm3_body(u, p.x, p.ridx, p.cidx, p.Bph, p.Bpl, p.qsel, p.ksel, p.vsel);
    grid.sync();
    // S7 attn
    for (int u = blockIdx.x; u < 512; u += nb) {
        attn_body(u, p.qsel, p.ksel, p.vsel, p.sv, p.delta, sh.s7);
        __syncthreads();
    }
    grid.sync();
    // S8 deltamm_ub
    for (int u = blockIdx.x; u < 544; u += nb) {
        deltamm_body(u, p.delta, p.w_out, p.b_out, p.sv, p.deltaout, p.ubase, sh.s8);
        __syncthreads();
    }
    grid.sync();
    // S9 compose
    for (int u = blockIdx.x; u < 2048; u += nb)
        compose_body(u, p.ubase, p.rankmap, p.deltaout, p.out);
}

// =================================================================
extern "C" void kernel_launch(void* const* d_in, const int* in_sizes, int n_in,
                              void* d_out, int out_size, void* d_ws, size_t ws_size,
                              hipStream_t stream) {
    const float* x     = (const float*)d_in[0];
    const float* w_qkv = (const float*)d_in[1];
    const float* w_out = (const float*)d_in[2];
    const float* b_out = (const float*)d_in[3];
    float* out = (float*)d_out;

    float* ws = (float*)d_ws;
    float* xpart   = ws;                            // 262144 f
    float* spart   = xpart + 262144;                // 98304 f
    float* sv      = spart + 98304;                 // 2048 f
    float* rvec    = sv + 2048;                     // 16384 f
    float* cvec    = rvec + 16384;
    float* rsc     = cvec + 16384;                  // 65536 f
    float* csc     = rsc + 65536;
    int*   ridx    = (int*)(csc + 65536);           // 8192 i
    int*   cidx    = ridx + 8192;
    int*   rankmap = cidx + 8192;                   // 65536 i
    float* ubase   = (float*)(rankmap + 65536);     // 2048 f
    bf16x8* Bp_hi  = (bf16x8*)(ubase + 2048);       // 393216 f
    bf16x8* Bp_lo  = (bf16x8*)((float*)Bp_hi + 393216);
    float* qsel    = (float*)Bp_lo + 393216;        // 524288 f
    float* ksel    = qsel + 524288;
    float* vsel    = ksel + 524288;
    float* delta   = vsel + 524288;                 // 524288 f
    float* deltaout = delta + 524288;               // 4194304 f

    // cooperative grid size (cached): 2 blocks/CU if LDS allows, else 1.
    static int fgrid = 0;
    if (fgrid == 0) {
        int nb = 0;
        if (hipOccupancyMaxActiveBlocksPerMultiprocessor(&nb, fused_all, 256, 0) != hipSuccess || nb < 1)
            nb = 1;
        fgrid = (nb >= 2) ? 512 : 256;
    }

    Params P;
    P.x = x; P.w_qkv = w_qkv; P.w_out = w_out; P.b_out = b_out; P.out = out;
    P.xpart = xpart; P.spart = spart; P.sv = sv; P.rvec = rvec; P.cvec = cvec;
    P.rsc = rsc; P.csc = csc; P.ridx = ridx; P.cidx = cidx; P.rankmap = rankmap;
    P.ubase = ubase; P.Bph = Bp_hi; P.Bpl = Bp_lo; P.BphW = Bp_hi; P.BplW = Bp_lo;
    P.qsel = qsel; P.ksel = ksel; P.vsel = vsel; P.delta = delta; P.deltaout = deltaout;

    void* kargs[] = { (void*)&P };
    hipError_t err = hipLaunchCooperativeKernel((const void*)fused_all,
                                                dim3(fgrid), dim3(256),
                                                kargs, 0, stream);
    if (err != hipSuccess) {
        // fallback: exact round-8 launch sequence
        prep_k<<<896, 256, 0, stream>>>(w_qkv, Bp_hi, Bp_lo, x, xpart);
        statsA_k<<<384, 256, 0, stream>>>(xpart, w_qkv, spart);
        statsB_k<<<64, 256, 0, stream>>>(spart, w_qkv, sv, rvec, cvec);
        score3_k<<<512, 256, 0, stream>>>(x, rvec, cvec, rsc, csc);
        topk4_k<<<64, 256, 0, stream>>>(rsc, csc, ridx, cidx, rankmap);
        selgemm3_k<<<384, 256, 0, stream>>>(x, ridx, cidx, Bp_hi, Bp_lo, qsel, ksel, vsel);
        attn_k<<<512, 256, 0, stream>>>(qsel, ksel, vsel, sv, delta);
        deltamm_k<<<544, 256, 0, stream>>>(delta, w_out, b_out, sv, deltaout, ubase);
        compose_k<<<2048, 256, 0, stream>>>(ubase, rankmap, deltaout, out);
    }
}

// Round 10
// 175.276 us; speedup vs baseline: 2.8195x; 2.8195x over previous
//
#include <hip/hip_runtime.h>
#include <math.h>

#define Bsz 4
#define Nseq 2048
#define Cdim 512
#define Hn 8
#define Dh 64
#define TK 256
#define BH (Bsz*Hn)          // 32
#define QKVC 1536

typedef __attribute__((ext_vector_type(8))) short bf16x8;
typedef __attribute__((ext_vector_type(4))) float f32x4;

__device__ __forceinline__ unsigned short f2bf(float x) {
    unsigned u = __float_as_uint(x);
    unsigned r = (u + 0x7fffu + ((u >> 16) & 1u)) >> 16;   // round-to-nearest-even
    return (unsigned short)r;
}
__device__ __forceinline__ float bf2f(unsigned short h) {
    return __uint_as_float((unsigned)h << 16);
}
__device__ __forceinline__ f32x4 mfma16(bf16x8 a, bf16x8 b, f32x4 c) {
    return __builtin_amdgcn_mfma_f32_16x16x32_bf16(a, b, c, 0, 0, 0);
}

// ---------------------------------------------------------------
// xprep: partial column sums of x, 16-row chunks. grid 512.
// (bit-identical to round-8 prep else-branch)
// ---------------------------------------------------------------
__global__ __launch_bounds__(256) void xprep(const float* __restrict__ x,
                                             float* __restrict__ xpart) {
    int r = blockIdx.x;                  // 0..511
    int tid = threadIdx.x;
    int b = r >> 7, rc = r & 127;
    const float* xp = x + ((size_t)b * Nseq + rc * 16) * Cdim;
    float s0 = 0.f, s1 = 0.f;
    #pragma unroll 4
    for (int rr = 0; rr < 16; ++rr) {
        s0 += xp[rr * Cdim + tid];
        s1 += xp[rr * Cdim + 256 + tid];
    }
    xpart[((size_t)b * 128 + rc) * Cdim + tid] = s0;
    xpart[((size_t)b * 128 + rc) * Cdim + 256 + tid] = s1;
}

// ---------------------------------------------------------------
// statsAW: block-range fusion.
//  blocks [0,384):   statsA partial stats GEMM (b=u&3, kc=(u>>2)&15, nb=u>>6)
//  blocks [384,768): W-pack w_qkv -> hi/lo bf16 fragments (independent;
//                    first consumed at selgemm — moved off pipeline head)
// ---------------------------------------------------------------
__global__ __launch_bounds__(256) void statsAW(const float* __restrict__ xpart,
                                               const float* __restrict__ w_qkv,
                                               float* __restrict__ spart,
                                               bf16x8* __restrict__ hi,
                                               bf16x8* __restrict__ lo) {
    int bid = blockIdx.x;
    int t = threadIdx.x;
    if (bid < 384) {
        int b = bid & 3, kc = (bid >> 2) & 15, nb = bid >> 6;
        __shared__ float xr[8][32];
        __shared__ float xs[32];
        int i = t & 31, g = t >> 5;
        float s = 0.f;
        #pragma unroll 4
        for (int j = 0; j < 16; ++j)
            s += xpart[((size_t)b * 128 + g * 16 + j) * Cdim + kc * 32 + i];
        xr[g][i] = s;
        __syncthreads();
        if (t < 32) {
            float v = 0.f;
            #pragma unroll
            for (int gg = 0; gg < 8; ++gg) v += xr[gg][t];
            xs[t] = v;
        }
        __syncthreads();
        float a0 = 0.f;
        const float* wbase = w_qkv + (size_t)(kc * 32) * QKVC + nb * 256 + t;
        #pragma unroll 4
        for (int i2 = 0; i2 < 32; ++i2)
            a0 += xs[i2] * wbase[(size_t)i2 * QKVC];
        spart[(size_t)(b * 16 + kc) * QKVC + nb * 256 + t] = a0;
    } else {
        int u = bid - 384;                   // 0..383
        int nt = u >> 2;                     // 0..95
        int kt = (u & 3) * 4 + (t >> 6);     // 0..15
        int lane = t & 63;
        int c = nt * 16 + (lane & 15);
        int kbase = kt * 32 + (lane >> 4) * 8;
        bf16x8 h, l;
        #pragma unroll
        for (int j = 0; j < 8; ++j) {
            float v = w_qkv[(size_t)(kbase + j) * QKVC + c];
            unsigned short hv = f2bf(v);
            h[j] = (short)hv;
            l[j] = (short)f2bf(v - bf2f(hv));
        }
        int idx = (nt * 16 + kt) * 64 + lane;
        hi[idx] = h;
        lo[idx] = l;
    }
}

// ---------------------------------------------------------------
// statsB: finalize qm/km/sv from spart (16 chunks), then rvec/cvec.
// grid (32 bh, 2 cb).  (unchanged round 8)
// ---------------------------------------------------------------
__global__ __launch_bounds__(256) void statsB(const float* __restrict__ spart,
                                              const float* __restrict__ w_qkv,
                                              float* __restrict__ sv,
                                              float* __restrict__ rvec,
                                              float* __restrict__ cvec) {
    int bh = blockIdx.x, cb = blockIdx.y;
    int b = bh >> 3, h = bh & 7;
    __shared__ float qm[64], km[64];
    int t = threadIdx.x;
    if (t < 192) {
        int which = t >> 6, d = t & 63;
        int col = which * 512 + h * 64 + d;
        float s = 0.f;
        #pragma unroll
        for (int kc = 0; kc < 16; ++kc)
            s += spart[(size_t)(b * 16 + kc) * QKVC + col];
        if (which == 0)      qm[d] = s * (1.0f / Nseq);
        else if (which == 1) km[d] = s * (1.0f / Nseq);
        else if (cb == 0)    sv[bh * 64 + d] = s;
    }
    __syncthreads();
    int c = cb * 256 + t;
    const float4* wr = (const float4*)(w_qkv + (size_t)c * QKVC + h * 64);
    const float4* wc = (const float4*)(w_qkv + (size_t)c * QKVC + 512 + h * 64);
    float r = 0.f, cv = 0.f;
    #pragma unroll
    for (int d4 = 0; d4 < 16; ++d4) {
        float4 w1 = wr[d4], w2 = wc[d4];
        float4 k1 = *(const float4*)&km[d4 * 4];
        float4 q1 = *(const float4*)&qm[d4 * 4];
        r  += w1.x * k1.x + w1.y * k1.y + w1.z * k1.z + w1.w * k1.w;
        cv += w2.x * q1.x + w2.y * q1.y + w2.z * q1.z + w2.w * q1.w;
    }
    rvec[(size_t)bh * Cdim + c] = r;
    cvec[(size_t)bh * Cdim + c] = cv;
}

// ---------------------------------------------------------------
// score4: single-pass rank-1 scores.  grid (4 b, 128 rc), 128 threads.
// 16 rows/block; both rvec+cvec staged (34.8 KB LDS) -> x read ONCE.
// Per-thread dots and shfl trees bit-identical to round 8.
// ---------------------------------------------------------------
__global__ __launch_bounds__(128) void score4_kernel(const float* __restrict__ x,
                                                     const float* __restrict__ rvec,
                                                     const float* __restrict__ cvec,
                                                     float* __restrict__ rsc,
                                                     float* __restrict__ csc) {
    int b = blockIdx.x, rc = blockIdx.y;
    __shared__ float vs[16 * 8 * 68];     // 34.8 KB
    int t = threadIdx.x;
    int r = t >> 3, g = t & 7;            // 16 rows x 8 col-groups

    const float4* xp = (const float4*)(x + ((size_t)b * Nseq + rc * 16 + r) * Cdim + g * 64);
    float4 xr[16];
    #pragma unroll
    for (int j4 = 0; j4 < 16; ++j4) xr[j4] = xp[j4];

    {
        const float4* rp = (const float4*)(rvec + (size_t)b * 8 * Cdim);
        const float4* cp = (const float4*)(cvec + (size_t)b * 8 * Cdim);
        for (int i = t; i < 16 * 128; i += 128) {
            int v = i >> 7, c4 = i & 127;
            float4 val = (v < 8) ? rp[v * 128 + c4] : cp[(v - 8) * 128 + c4];
            int gg = c4 >> 4, j4 = c4 & 15;
            *(float4*)&vs[(v * 8 + gg) * 68 + j4 * 4] = val;
        }
    }
    __syncthreads();

    float acc[16];
    #pragma unroll
    for (int v = 0; v < 16; ++v) acc[v] = 0.f;
    #pragma unroll
    for (int j4 = 0; j4 < 16; ++j4) {
        float4 xv = xr[j4];
        #pragma unroll
        for (int v = 0; v < 16; ++v) {
            float4 wv = *(const float4*)&vs[(v * 8 + g) * 68 + j4 * 4];
            acc[v] += xv.x * wv.x + xv.y * wv.y + xv.z * wv.z + xv.w * wv.w;
        }
    }
    #pragma unroll
    for (int v = 0; v < 16; ++v) {
        float s = acc[v];
        s += __shfl_xor(s, 1, 64);
        s += __shfl_xor(s, 2, 64);
        s += __shfl_xor(s, 4, 64);
        acc[v] = s;
    }
    if (g == 0) {
        int i = rc * 16 + r;
        #pragma unroll
        for (int v = 0; v < 8; ++v) {
            rsc[(size_t)(b * 8 + v) * Nseq + i] = acc[v] * 0.125f;
            csc[(size_t)(b * 8 + v) * Nseq + i] = acc[8 + v] * 0.125f;
        }
    }
}

// ---------------------------------------------------------------
// topk4: radix-select top-256 (O(N)).  grid 64.  (unchanged round 8)
// ---------------------------------------------------------------
__global__ __launch_bounds__(256) void topk4(const float* __restrict__ rsc,
                                             const float* __restrict__ csc,
                                             int* __restrict__ ridx,
                                             int* __restrict__ cidx,
                                             int* __restrict__ rankmap) {
    int selid = blockIdx.x;
    int bh = selid >> 1, which = selid & 1;
    const float* sin = which ? (csc + (size_t)bh * Nseq) : (rsc + (size_t)bh * Nseq);
    __shared__ int hist[256];
    __shared__ int sS[256];
    __shared__ int tieidx[2048];
    __shared__ int sh_D, sh_above, sh_tiecnt;
    int tid = threadIdx.x;

    unsigned k[8];
    #pragma unroll
    for (int j = 0; j < 8; ++j) {
        unsigned u = __float_as_uint(sin[j * 256 + tid]);
        k[j] = (u & 0x80000000u) ? ~u : (u | 0x80000000u);
    }

    unsigned pref = 0;
    int above = 0;
    for (int level = 3; level >= 0; --level) {
        hist[tid] = 0;
        __syncthreads();
        int sh = level * 8;
        #pragma unroll
        for (int j = 0; j < 8; ++j) {
            bool match;
            if (level == 3) match = true;
            else            match = ((k[j] >> (sh + 8)) == pref);
            if (match) atomicAdd(&hist[(k[j] >> sh) & 255], 1);
        }
        __syncthreads();
        sS[tid] = hist[tid];
        __syncthreads();
        for (int off = 1; off < 256; off <<= 1) {
            int v = (tid + off < 256) ? sS[tid + off] : 0;
            __syncthreads();
            sS[tid] += v;
            __syncthreads();
        }
        int Sincl = sS[tid];
        int Sexcl = (tid < 255) ? sS[tid + 1] : 0;
        if (above + Sexcl < TK && above + Sincl >= TK) {
            sh_D = tid;
            sh_above = above + Sexcl;
        }
        __syncthreads();
        pref = (pref << 8) | (unsigned)sh_D;
        above = sh_above;
        __syncthreads();
    }
    unsigned T = pref;
    int rem = TK - above;

    if (tid == 0) sh_tiecnt = 0;
    __syncthreads();
    int cnt = 0;
    #pragma unroll
    for (int j = 0; j < 8; ++j) {
        if (k[j] > T) ++cnt;
        if (k[j] == T) {
            int p = atomicAdd(&sh_tiecnt, 1);
            tieidx[p] = j * 256 + tid;
        }
    }
    sS[tid] = cnt;
    __syncthreads();
    for (int off = 1; off < 256; off <<= 1) {
        int v = (tid >= off) ? sS[tid - off] : 0;
        __syncthreads();
        sS[tid] += v;
        __syncthreads();
    }
    int base = sS[tid] - cnt;
    int tc = sh_tiecnt;
    int* outp = which ? (cidx + bh * TK) : (ridx + bh * TK);
    #pragma unroll
    for (int j = 0; j < 8; ++j) {
        int i = j * 256 + tid;
        int r = -1;
        if (k[j] > T) {
            r = base++;
        } else if (k[j] == T) {
            int rk = 0;
            for (int t2 = 0; t2 < tc; ++t2) rk += (tieidx[t2] < i) ? 1 : 0;
            if (rk < rem) r = above + rk;
        }
        if (r >= 0) outp[r] = i;
        if (which == 0) rankmap[(size_t)bh * Nseq + i] = r;
    }
}

// ---------------------------------------------------------------
// selgemm3: barrier-free gather-GEMM, NI=4.  (unchanged round 8)
// grid (4 mq, 3 part, 32 bh).
// ---------------------------------------------------------------
__global__ __launch_bounds__(256) void selgemm3(const float* __restrict__ x,
                                                const int* __restrict__ ridx,
                                                const int* __restrict__ cidx,
                                                const bf16x8* __restrict__ Bph,
                                                const bf16x8* __restrict__ Bpl,
                                                float* __restrict__ qsel,
                                                float* __restrict__ ksel,
                                                float* __restrict__ vsel) {
    int mq = blockIdx.x, part = blockIdx.y, bh = blockIdx.z;
    int b = bh >> 3, h = bh & 7;
    int tid = threadIdx.x;
    int wv = tid >> 6, lane = tid & 63;
    const int* idxp = (part == 0 ? ridx : cidx) + bh * TK + mq * 64 + wv * 16;
    int row = idxp[lane & 15];
    const float* ap = x + ((size_t)b * Nseq + row) * Cdim + (lane >> 4) * 8;
    size_t orow = (size_t)bh * TK + mq * 64 + wv * 16;
    int nt0 = (part == 0) ? (h * 4) : (part == 1 ? (32 + h * 4) : (64 + h * 4));
    float* outp = (part == 0) ? qsel : (part == 1 ? ksel : vsel);

    f32x4 acc[4];
    #pragma unroll
    for (int i = 0; i < 4; ++i) acc[i] = (f32x4){0.f, 0.f, 0.f, 0.f};
    float4 a0 = *(const float4*)ap;
    float4 a1 = *(const float4*)(ap + 4);
    #pragma unroll 2
    for (int kt = 0; kt < 16; ++kt) {
        float4 na0 = a0, na1 = a1;
        if (kt < 15) {
            na0 = *(const float4*)(ap + (kt + 1) * 32);
            na1 = *(const float4*)(ap + (kt + 1) * 32 + 4);
        }
        float vv[8] = {a0.x, a0.y, a0.z, a0.w, a1.x, a1.y, a1.z, a1.w};
        bf16x8 ah, al;
        #pragma unroll
        for (int j = 0; j < 8; ++j) {
            unsigned short hv = f2bf(vv[j]);
            ah[j] = (short)hv;
            al[j] = (short)f2bf(vv[j] - bf2f(hv));
        }
        #pragma unroll
        for (int ni = 0; ni < 4; ++ni) {
            int nt16 = nt0 + ni;
            bf16x8 bh8 = Bph[((size_t)nt16 * 16 + kt) * 64 + lane];
            bf16x8 bl8 = Bpl[((size_t)nt16 * 16 + kt) * 64 + lane];
            acc[ni] = mfma16(ah, bh8, acc[ni]);
            acc[ni] = mfma16(ah, bl8, acc[ni]);
            acc[ni] = mfma16(al, bh8, acc[ni]);
        }
        a0 = na0; a1 = na1;
    }
    int cl = lane & 15, rq = (lane >> 4) * 4;
    #pragma unroll
    for (int ni = 0; ni < 4; ++ni) {
        int csub = ni * 16 + cl;
        #pragma unroll
        for (int r = 0; r < 4; ++r)
            outp[(orow + rq + r) * 64 + csub] = acc[ni][r];
    }
}

// ---------------------------------------------------------------
// attn_fused3: grid (32 bh, 16 rblk).  (unchanged round 8)
// ---------------------------------------------------------------
__global__ __launch_bounds__(256) void attn_fused3(const float* __restrict__ qsel,
                                                   const float* __restrict__ ksel,
                                                   const float* __restrict__ vsel,
                                                   const float* __restrict__ sv,
                                                   float* __restrict__ delta) {
    int bh = blockIdx.x;
    int rblk = blockIdx.y;
    __shared__ float Kt[64 * 256];       // 64 KB; E[16][256] aliases after QK
    __shared__ float Qs[16 * 64];        // 4 KB
    __shared__ float umS[16], izS[16];
    int tid = threadIdx.x;
    {
        int j = tid;
        const float4* kp4 = (const float4*)(ksel + ((size_t)bh * TK + j) * 64);
        #pragma unroll
        for (int d4 = 0; d4 < 16; ++d4) {
            float4 kv = kp4[d4];
            Kt[(d4 * 4 + 0) * 256 + j] = kv.x;
            Kt[(d4 * 4 + 1) * 256 + j] = kv.y;
            Kt[(d4 * 4 + 2) * 256 + j] = kv.z;
            Kt[(d4 * 4 + 3) * 256 + j] = kv.w;
        }
    }
    for (int idx = tid; idx < 16 * 64; idx += 256)
        Qs[idx] = qsel[((size_t)bh * TK + rblk * 16) * 64 + idx];
    __syncthreads();

    int wave = tid >> 6, lane = tid & 63;
    int iw0 = wave * 4;
    float e[4][4];
    #pragma unroll
    for (int r = 0; r < 4; ++r)
        #pragma unroll
        for (int t = 0; t < 4; ++t) e[r][t] = 0.f;
    #pragma unroll 8
    for (int d = 0; d < 64; ++d) {
        float4 kv = *(const float4*)&Kt[d * 256 + 4 * lane];
        #pragma unroll
        for (int r = 0; r < 4; ++r) {
            float qd = Qs[(iw0 + r) * 64 + d];
            e[r][0] += qd * kv.x; e[r][1] += qd * kv.y;
            e[r][2] += qd * kv.z; e[r][3] += qd * kv.w;
        }
    }
    #pragma unroll
    for (int r = 0; r < 4; ++r) {
        float s0 = e[r][0] * 0.125f, s1 = e[r][1] * 0.125f;
        float s2 = e[r][2] * 0.125f, s3 = e[r][3] * 0.125f;
        float mx = fmaxf(fmaxf(s0, s1), fmaxf(s2, s3));
        #pragma unroll
        for (int off = 32; off; off >>= 1) mx = fmaxf(mx, __shfl_xor(mx, off, 64));
        mx = fmaxf(mx, 0.0f);
        float e0 = __expf(s0 - mx), e1 = __expf(s1 - mx);
        float e2 = __expf(s2 - mx), e3 = __expf(s3 - mx);
        float zs = e0 + e1 + e2 + e3;
        #pragma unroll
        for (int off = 32; off; off >>= 1) zs += __shfl_xor(zs, off, 64);
        if (lane == 0) {
            float em = __expf(-mx);
            umS[iw0 + r] = em;
            izS[iw0 + r] = 1.0f / ((float)(Nseq - TK) * em + zs);
        }
        e[r][0] = e0; e[r][1] = e1; e[r][2] = e2; e[r][3] = e3;
    }
    __syncthreads();
    float* E = Kt;
    #pragma unroll
    for (int r = 0; r < 4; ++r)
        *(float4*)&E[(iw0 + r) * 256 + 4 * lane] = (float4){e[r][0], e[r][1], e[r][2], e[r][3]};
    __syncthreads();

    const float* vbase = vsel + (size_t)bh * TK * 64 + lane;
    float ssel = 0.f;
    float acc[4];
    #pragma unroll
    for (int r = 0; r < 4; ++r) acc[r] = 0.f;
    #pragma unroll 4
    for (int j = 0; j < TK; ++j) {
        float v = vbase[j * 64];
        ssel += v;
        #pragma unroll
        for (int r = 0; r < 4; ++r)
            acc[r] += E[(iw0 + r) * 256 + j] * v;
    }
    float svd = sv[bh * 64 + lane];
    float sadj = svd - ssel;
    float uval = svd * (1.0f / Nseq);
    #pragma unroll
    for (int r = 0; r < 4; ++r) {
        int i = rblk * 16 + iw0 + r;
        float outv = (umS[iw0 + r] * sadj + acc[r]) * izS[iw0 + r];
        delta[((size_t)bh * TK + i) * 64 + lane] = outv - uval;
    }
}

// ---------------------------------------------------------------
// deltamm_ub: 64-row tiles.  (unchanged round 8)
//  blocks [0,512): deltaout tile ; blocks [512,544): ubase
// ---------------------------------------------------------------
__global__ __launch_bounds__(256) void deltamm_ub(const float* __restrict__ delta,
                                                  const float* __restrict__ w_out,
                                                  const float* __restrict__ b_out,
                                                  const float* __restrict__ sv,
                                                  float* __restrict__ deltaout,
                                                  float* __restrict__ ubase) {
    int bid = blockIdx.x;
    int tid = threadIdx.x;
    if (bid < 512) {
        int bh = bid >> 4, sub = bid & 15;
        int rh = sub >> 2, ct = sub & 3;
        int h = bh & 7;
        __shared__ float As[64][65];
        __shared__ float Ws[64][132];
        for (int idx = tid; idx < 64 * 64; idx += 256) {
            int row = idx >> 6, k = idx & 63;
            As[row][k] = delta[((size_t)bh * TK + rh * 64 + row) * 64 + k];
        }
        for (int idx = tid; idx < 64 * 128; idx += 256) {
            int k = idx >> 7, c = idx & 127;
            Ws[k][c] = w_out[(size_t)(h * 64 + k) * 512 + ct * 128 + c];
        }
        __syncthreads();
        int tx = tid & 15, ty = tid >> 4;
        float acc[4][8];
        #pragma unroll
        for (int r = 0; r < 4; ++r)
            #pragma unroll
            for (int c = 0; c < 8; ++c) acc[r][c] = 0.f;
        for (int k = 0; k < 64; ++k) {
            float a[4], bv[8];
            #pragma unroll
            for (int r = 0; r < 4; ++r) a[r] = As[ty * 4 + r][k];
            #pragma unroll
            for (int cc = 0; cc < 4; ++cc) {
                bv[cc]     = Ws[k][tx * 4 + cc];
                bv[4 + cc] = Ws[k][64 + tx * 4 + cc];
            }
            #pragma unroll
            for (int r = 0; r < 4; ++r)
                #pragma unroll
                for (int c = 0; c < 8; ++c) acc[r][c] += a[r] * bv[c];
        }
        #pragma unroll
        for (int r = 0; r < 4; ++r) {
            size_t ro = ((size_t)bh * TK + rh * 64 + ty * 4 + r) * 512 + ct * 128;
            #pragma unroll
            for (int cc = 0; cc < 4; ++cc) {
                deltaout[ro + tx * 4 + cc]      = acc[r][cc];
                deltaout[ro + 64 + tx * 4 + cc] = acc[r][4 + cc];
            }
        }
    } else {
        int r2 = bid - 512;
        int b = r2 >> 3;
        int c0 = (r2 & 7) * 64;
        int c = tid & 63, kg = tid >> 6;
        float s = 0.f;
        for (int k = kg * 128; k < kg * 128 + 128; ++k) {
            float hu = sv[(b * 8 + (k >> 6)) * 64 + (k & 63)] * (1.0f / Nseq);
            s += hu * w_out[(size_t)k * 512 + c0 + c];
        }
        __shared__ float red[4][64];
        red[kg][c] = s;
        __syncthreads();
        if (tid < 64)
            ubase[b * 512 + c0 + c] = red[0][c] + red[1][c] + red[2][c] + red[3][c] + b_out[c0 + c];
    }
}

// ---------------------------------------------------------------
// compose: out = ubase + gathered deltaout.  (unchanged round 8)
// ---------------------------------------------------------------
__global__ __launch_bounds__(256) void compose(const float* __restrict__ ubase,
                                               const int* __restrict__ rankmap,
                                               const float* __restrict__ deltaout,
                                               float* __restrict__ out) {
    int r0 = blockIdx.x * 4;
    int b = r0 >> 11;
    int tid = threadIdx.x;
    float u0 = ubase[b * 512 + tid];
    float u1 = ubase[b * 512 + 256 + tid];
    for (int rr = 0; rr < 4; ++rr) {
        int i = (r0 + rr) & 2047;
        float a0 = u0, a1 = u1;
        #pragma unroll
        for (int h = 0; h < 8; ++h) {
            int rk = rankmap[(size_t)(b * 8 + h) * Nseq + i];
            if (rk >= 0) {
                const float* dp = deltaout + ((size_t)(b * 8 + h) * TK + rk) * 512;
                a0 += dp[tid];
                a1 += dp[256 + tid];
            }
        }
        float* op = out + ((size_t)b * Nseq + i) * 512;
        op[tid] = a0;
        op[256 + tid] = a1;
    }
}

extern "C" void kernel_launch(void* const* d_in, const int* in_sizes, int n_in,
                              void* d_out, int out_size, void* d_ws, size_t ws_size,
                              hipStream_t stream) {
    const float* x     = (const float*)d_in[0];
    const float* w_qkv = (const float*)d_in[1];
    const float* w_out = (const float*)d_in[2];
    const float* b_out = (const float*)d_in[3];
    float* out = (float*)d_out;

    float* ws = (float*)d_ws;
    float* xpart   = ws;                            // 262144 f
    float* spart   = xpart + 262144;                // 98304 f
    float* sv      = spart + 98304;                 // 2048 f
    float* rvec    = sv + 2048;                     // 16384 f
    float* cvec    = rvec + 16384;
    float* rsc     = cvec + 16384;                  // 65536 f
    float* csc     = rsc + 65536;
    int*   ridx    = (int*)(csc + 65536);           // 8192 i
    int*   cidx    = ridx + 8192;
    int*   rankmap = cidx + 8192;                   // 65536 i
    float* ubase   = (float*)(rankmap + 65536);     // 2048 f
    bf16x8* Bp_hi  = (bf16x8*)(ubase + 2048);       // 393216 f
    bf16x8* Bp_lo  = (bf16x8*)((float*)Bp_hi + 393216);
    float* qsel    = (float*)Bp_lo + 393216;        // 524288 f
    float* ksel    = qsel + 524288;
    float* vsel    = ksel + 524288;
    float* delta   = vsel + 524288;                 // 524288 f
    float* deltaout = delta + 524288;               // 4194304 f

    // 1. x column partial sums only (W-pack moved off the pipeline head)
    xprep<<<512, 256, 0, stream>>>(x, xpart);
    // 2. partial stats GEMM + W fragment packing (independent, fused)
    statsAW<<<768, 256, 0, stream>>>(xpart, w_qkv, spart, Bp_hi, Bp_lo);
    // 3. finalize qm/km/sv + folded score vectors
    statsB<<<dim3(BH, 2), 256, 0, stream>>>(spart, w_qkv, sv, rvec, cvec);
    // 4. rank-1 scores, single pass over x (both halves per block)
    score4_kernel<<<dim3(Bsz, 128), 128, 0, stream>>>(x, rvec, cvec, rsc, csc);
    // 5. top-256 + rankmap via radix-select
    topk4<<<BH * 2, 256, 0, stream>>>(rsc, csc, ridx, cidx, rankmap);
    // 6. barrier-free gather-GEMM
    selgemm3<<<dim3(4, 3, BH), 256, 0, stream>>>(x, ridx, cidx, Bp_hi, Bp_lo, qsel, ksel, vsel);
    // 7. fused attention -> compact delta
    attn_fused3<<<dim3(BH, 16), 256, 0, stream>>>(qsel, ksel, vsel, sv, delta);
    // 8. delta @ w_out + uniform base rows
    deltamm_ub<<<544, 256, 0, stream>>>(delta, w_out, b_out, sv, deltaout, ubase);
    // 9. compose final output
    compose<<<Bsz * Nseq / 4, 256, 0, stream>>>(ubase, rankmap, deltaout, out);
}

// Round 11
// 172.135 us; speedup vs baseline: 2.8709x; 1.0182x over previous
//
#include <hip/hip_runtime.h>
#include <math.h>

#define Bsz 4
#define Nseq 2048
#define Cdim 512
#define Hn 8
#define Dh 64
#define TK 256
#define BH (Bsz*Hn)          // 32
#define QKVC 1536

typedef __attribute__((ext_vector_type(8))) short bf16x8;
typedef __attribute__((ext_vector_type(4))) float f32x4;

__device__ __forceinline__ unsigned short f2bf(float x) {
    unsigned u = __float_as_uint(x);
    unsigned r = (u + 0x7fffu + ((u >> 16) & 1u)) >> 16;   // round-to-nearest-even
    return (unsigned short)r;
}
__device__ __forceinline__ float bf2f(unsigned short h) {
    return __uint_as_float((unsigned)h << 16);
}
__device__ __forceinline__ f32x4 mfma16(bf16x8 a, bf16x8 b, f32x4 c) {
    return __builtin_amdgcn_mfma_f32_16x16x32_bf16(a, b, c, 0, 0, 0);
}

// ---------------------------------------------------------------
// xprep: partial column sums of x, 16-row chunks. grid 512.
// ---------------------------------------------------------------
__global__ __launch_bounds__(256) void xprep(const float* __restrict__ x,
                                             float* __restrict__ xpart) {
    int r = blockIdx.x;                  // 0..511
    int tid = threadIdx.x;
    int b = r >> 7, rc = r & 127;
    const float* xp = x + ((size_t)b * Nseq + rc * 16) * Cdim;
    float s0 = 0.f, s1 = 0.f;
    #pragma unroll 4
    for (int rr = 0; rr < 16; ++rr) {
        s0 += xp[rr * Cdim + tid];
        s1 += xp[rr * Cdim + 256 + tid];
    }
    xpart[((size_t)b * 128 + rc) * Cdim + tid] = s0;
    xpart[((size_t)b * 128 + rc) * Cdim + 256 + tid] = s1;
}

// ---------------------------------------------------------------
// statsAW: block-range fusion.
//  blocks [0,384):   statsA partial stats GEMM
//  blocks [384,768): W-pack w_qkv -> hi/lo bf16 fragments
// ---------------------------------------------------------------
__global__ __launch_bounds__(256) void statsAW(const float* __restrict__ xpart,
                                               const float* __restrict__ w_qkv,
                                               float* __restrict__ spart,
                                               bf16x8* __restrict__ hi,
                                               bf16x8* __restrict__ lo) {
    int bid = blockIdx.x;
    int t = threadIdx.x;
    if (bid < 384) {
        int b = bid & 3, kc = (bid >> 2) & 15, nb = bid >> 6;
        __shared__ float xr[8][32];
        __shared__ float xs[32];
        int i = t & 31, g = t >> 5;
        float s = 0.f;
        #pragma unroll 4
        for (int j = 0; j < 16; ++j)
            s += xpart[((size_t)b * 128 + g * 16 + j) * Cdim + kc * 32 + i];
        xr[g][i] = s;
        __syncthreads();
        if (t < 32) {
            float v = 0.f;
            #pragma unroll
            for (int gg = 0; gg < 8; ++gg) v += xr[gg][t];
            xs[t] = v;
        }
        __syncthreads();
        float a0 = 0.f;
        const float* wbase = w_qkv + (size_t)(kc * 32) * QKVC + nb * 256 + t;
        #pragma unroll 4
        for (int i2 = 0; i2 < 32; ++i2)
            a0 += xs[i2] * wbase[(size_t)i2 * QKVC];
        spart[(size_t)(b * 16 + kc) * QKVC + nb * 256 + t] = a0;
    } else {
        int u = bid - 384;
        int nt = u >> 2;
        int kt = (u & 3) * 4 + (t >> 6);
        int lane = t & 63;
        int c = nt * 16 + (lane & 15);
        int kbase = kt * 32 + (lane >> 4) * 8;
        bf16x8 h, l;
        #pragma unroll
        for (int j = 0; j < 8; ++j) {
            float v = w_qkv[(size_t)(kbase + j) * QKVC + c];
            unsigned short hv = f2bf(v);
            h[j] = (short)hv;
            l[j] = (short)f2bf(v - bf2f(hv));
        }
        int idx = (nt * 16 + kt) * 64 + lane;
        hi[idx] = h;
        lo[idx] = l;
    }
}

// ---------------------------------------------------------------
// statsB: finalize qm/km/sv from spart, then rvec/cvec. grid (32, 2).
// ---------------------------------------------------------------
__global__ __launch_bounds__(256) void statsB(const float* __restrict__ spart,
                                              const float* __restrict__ w_qkv,
                                              float* __restrict__ sv,
                                              float* __restrict__ rvec,
                                              float* __restrict__ cvec) {
    int bh = blockIdx.x, cb = blockIdx.y;
    int b = bh >> 3, h = bh & 7;
    __shared__ float qm[64], km[64];
    int t = threadIdx.x;
    if (t < 192) {
        int which = t >> 6, d = t & 63;
        int col = which * 512 + h * 64 + d;
        float s = 0.f;
        #pragma unroll
        for (int kc = 0; kc < 16; ++kc)
            s += spart[(size_t)(b * 16 + kc) * QKVC + col];
        if (which == 0)      qm[d] = s * (1.0f / Nseq);
        else if (which == 1) km[d] = s * (1.0f / Nseq);
        else if (cb == 0)    sv[bh * 64 + d] = s;
    }
    __syncthreads();
    int c = cb * 256 + t;
    const float4* wr = (const float4*)(w_qkv + (size_t)c * QKVC + h * 64);
    const float4* wc = (const float4*)(w_qkv + (size_t)c * QKVC + 512 + h * 64);
    float r = 0.f, cv = 0.f;
    #pragma unroll
    for (int d4 = 0; d4 < 16; ++d4) {
        float4 w1 = wr[d4], w2 = wc[d4];
        float4 k1 = *(const float4*)&km[d4 * 4];
        float4 q1 = *(const float4*)&qm[d4 * 4];
        r  += w1.x * k1.x + w1.y * k1.y + w1.z * k1.z + w1.w * k1.w;
        cv += w2.x * q1.x + w2.y * q1.y + w2.z * q1.z + w2.w * q1.w;
    }
    rvec[(size_t)bh * Cdim + c] = r;
    cvec[(size_t)bh * Cdim + c] = cv;
}

// ---------------------------------------------------------------
// score4: single-pass rank-1 scores.  grid (4 b, 128 rc), 128 threads.
// ---------------------------------------------------------------
__global__ __launch_bounds__(128) void score4_kernel(const float* __restrict__ x,
                                                     const float* __restrict__ rvec,
                                                     const float* __restrict__ cvec,
                                                     float* __restrict__ rsc,
                                                     float* __restrict__ csc) {
    int b = blockIdx.x, rc = blockIdx.y;
    __shared__ float vs[16 * 8 * 68];     // 34.8 KB
    int t = threadIdx.x;
    int r = t >> 3, g = t & 7;

    const float4* xp = (const float4*)(x + ((size_t)b * Nseq + rc * 16 + r) * Cdim + g * 64);
    float4 xr[16];
    #pragma unroll
    for (int j4 = 0; j4 < 16; ++j4) xr[j4] = xp[j4];

    {
        const float4* rp = (const float4*)(rvec + (size_t)b * 8 * Cdim);
        const float4* cp = (const float4*)(cvec + (size_t)b * 8 * Cdim);
        for (int i = t; i < 16 * 128; i += 128) {
            int v = i >> 7, c4 = i & 127;
            float4 val = (v < 8) ? rp[v * 128 + c4] : cp[(v - 8) * 128 + c4];
            int gg = c4 >> 4, j4 = c4 & 15;
            *(float4*)&vs[(v * 8 + gg) * 68 + j4 * 4] = val;
        }
    }
    __syncthreads();

    float acc[16];
    #pragma unroll
    for (int v = 0; v < 16; ++v) acc[v] = 0.f;
    #pragma unroll
    for (int j4 = 0; j4 < 16; ++j4) {
        float4 xv = xr[j4];
        #pragma unroll
        for (int v = 0; v < 16; ++v) {
            float4 wv = *(const float4*)&vs[(v * 8 + g) * 68 + j4 * 4];
            acc[v] += xv.x * wv.x + xv.y * wv.y + xv.z * wv.z + xv.w * wv.w;
        }
    }
    #pragma unroll
    for (int v = 0; v < 16; ++v) {
        float s = acc[v];
        s += __shfl_xor(s, 1, 64);
        s += __shfl_xor(s, 2, 64);
        s += __shfl_xor(s, 4, 64);
        acc[v] = s;
    }
    if (g == 0) {
        int i = rc * 16 + r;
        #pragma unroll
        for (int v = 0; v < 8; ++v) {
            rsc[(size_t)(b * 8 + v) * Nseq + i] = acc[v] * 0.125f;
            csc[(size_t)(b * 8 + v) * Nseq + i] = acc[8 + v] * 0.125f;
        }
    }
}

// ---------------------------------------------------------------
// topk5: radix-select top-256, scans via wave shfl (integer-exact,
// outputs bit-identical to topk4).  ~26 barriers vs ~110.
// grid 64.
// ---------------------------------------------------------------
__global__ __launch_bounds__(256) void topk5(const float* __restrict__ rsc,
                                             const float* __restrict__ csc,
                                             int* __restrict__ ridx,
                                             int* __restrict__ cidx,
                                             int* __restrict__ rankmap) {
    int selid = blockIdx.x;
    int bh = selid >> 1, which = selid & 1;
    const float* sin = which ? (csc + (size_t)bh * Nseq) : (rsc + (size_t)bh * Nseq);
    __shared__ int hist[256];
    __shared__ int wsum[4];
    __shared__ int tieidx[2048];
    __shared__ int sh_D, sh_above, sh_tiecnt;
    int tid = threadIdx.x;
    int lane = tid & 63, wv = tid >> 6;

    unsigned k[8];
    #pragma unroll
    for (int j = 0; j < 8; ++j) {
        unsigned u = __float_as_uint(sin[j * 256 + tid]);
        k[j] = (u & 0x80000000u) ? ~u : (u | 0x80000000u);
    }

    unsigned pref = 0;
    int above = 0;
    for (int level = 3; level >= 0; --level) {
        hist[tid] = 0;
        __syncthreads();
        int sh = level * 8;
        #pragma unroll
        for (int j = 0; j < 8; ++j) {
            bool match = (level == 3) || ((k[j] >> (sh + 8)) == pref);
            if (match) atomicAdd(&hist[(k[j] >> sh) & 255], 1);
        }
        __syncthreads();
        int h = hist[tid];
        // inclusive suffix scan: intra-wave shfl + wave-total combine
        int v = h;
        #pragma unroll
        for (int off = 1; off < 64; off <<= 1) {
            int tt = __shfl_down(v, off, 64);
            if (lane + off < 64) v += tt;
        }
        if (lane == 0) wsum[wv] = v;
        __syncthreads();
        int add = 0;
        #pragma unroll
        for (int w = 0; w < 4; ++w) if (w > wv) add += wsum[w];
        v += add;
        int Sincl = v, Sexcl = v - h;
        if (above + Sexcl < TK && above + Sincl >= TK) {
            sh_D = tid;
            sh_above = above + Sexcl;
        }
        __syncthreads();
        pref = (pref << 8) | (unsigned)sh_D;
        above = sh_above;
        __syncthreads();   // protect wsum/sh_D/hist reuse next level
    }
    unsigned T = pref;          // exact 256th-largest key
    int rem = TK - above;

    if (tid == 0) sh_tiecnt = 0;
    __syncthreads();
    int cnt = 0;
    #pragma unroll
    for (int j = 0; j < 8; ++j) {
        if (k[j] > T) ++cnt;
        if (k[j] == T) {
            int p = atomicAdd(&sh_tiecnt, 1);
            tieidx[p] = j * 256 + tid;
        }
    }
    // exclusive forward prefix scan of cnt (shfl + wave combine)
    int v = cnt;
    #pragma unroll
    for (int off = 1; off < 64; off <<= 1) {
        int tt = __shfl_up(v, off, 64);
        if (lane >= off) v += tt;
    }
    if (lane == 63) wsum[wv] = v;
    __syncthreads();            // also fences tie atomics + tieidx writes
    int add = 0;
    #pragma unroll
    for (int w = 0; w < 4; ++w) if (w < wv) add += wsum[w];
    int base = v + add - cnt;   // exclusive prefix of >T counts
    int tc = sh_tiecnt;
    int* outp = which ? (cidx + bh * TK) : (ridx + bh * TK);
    #pragma unroll
    for (int j = 0; j < 8; ++j) {
        int i = j * 256 + tid;
        int r = -1;
        if (k[j] > T) {
            r = base++;
        } else if (k[j] == T) {
            int rk = 0;
            for (int t2 = 0; t2 < tc; ++t2) rk += (tieidx[t2] < i) ? 1 : 0;
            if (rk < rem) r = above + rk;
        }
        if (r >= 0) outp[r] = i;
        if (which == 0) rankmap[(size_t)bh * Nseq + i] = r;
    }
}

// ---------------------------------------------------------------
// selgemm4: barrier-free gather-GEMM, NI=4, with 1-deep B-fragment
// register prefetch (pure load reordering; FP-identical).
// grid (4 mq, 3 part, 32 bh).
// ---------------------------------------------------------------
__global__ __launch_bounds__(256) void selgemm4(const float* __restrict__ x,
                                                const int* __restrict__ ridx,
                                                const int* __restrict__ cidx,
                                                const bf16x8* __restrict__ Bph,
                                                const bf16x8* __restrict__ Bpl,
                                                float* __restrict__ qsel,
                                                float* __restrict__ ksel,
                                                float* __restrict__ vsel) {
    int mq = blockIdx.x, part = blockIdx.y, bh = blockIdx.z;
    int b = bh >> 3, h = bh & 7;
    int tid = threadIdx.x;
    int wv = tid >> 6, lane = tid & 63;
    const int* idxp = (part == 0 ? ridx : cidx) + bh * TK + mq * 64 + wv * 16;
    int row = idxp[lane & 15];
    const float* ap = x + ((size_t)b * Nseq + row) * Cdim + (lane >> 4) * 8;
    size_t orow = (size_t)bh * TK + mq * 64 + wv * 16;
    int nt0 = (part == 0) ? (h * 4) : (part == 1 ? (32 + h * 4) : (64 + h * 4));
    float* outp = (part == 0) ? qsel : (part == 1 ? ksel : vsel);

    f32x4 acc[4];
    #pragma unroll
    for (int i = 0; i < 4; ++i) acc[i] = (f32x4){0.f, 0.f, 0.f, 0.f};

    bf16x8 bhc[4], blc[4];
    #pragma unroll
    for (int ni = 0; ni < 4; ++ni) {
        bhc[ni] = Bph[((size_t)(nt0 + ni) * 16 + 0) * 64 + lane];
        blc[ni] = Bpl[((size_t)(nt0 + ni) * 16 + 0) * 64 + lane];
    }
    float4 a0 = *(const float4*)ap;
    float4 a1 = *(const float4*)(ap + 4);
    #pragma unroll 2
    for (int kt = 0; kt < 16; ++kt) {
        float4 na0 = a0, na1 = a1;
        bf16x8 bhn[4], bln[4];
        if (kt < 15) {
            na0 = *(const float4*)(ap + (kt + 1) * 32);
            na1 = *(const float4*)(ap + (kt + 1) * 32 + 4);
            #pragma unroll
            for (int ni = 0; ni < 4; ++ni) {
                bhn[ni] = Bph[((size_t)(nt0 + ni) * 16 + (kt + 1)) * 64 + lane];
                bln[ni] = Bpl[((size_t)(nt0 + ni) * 16 + (kt + 1)) * 64 + lane];
            }
        }
        float vv[8] = {a0.x, a0.y, a0.z, a0.w, a1.x, a1.y, a1.z, a1.w};
        bf16x8 ah, al;
        #pragma unroll
        for (int j = 0; j < 8; ++j) {
            unsigned short hv = f2bf(vv[j]);
            ah[j] = (short)hv;
            al[j] = (short)f2bf(vv[j] - bf2f(hv));
        }
        #pragma unroll
        for (int ni = 0; ni < 4; ++ni) {
            acc[ni] = mfma16(ah, bhc[ni], acc[ni]);
            acc[ni] = mfma16(ah, blc[ni], acc[ni]);
            acc[ni] = mfma16(al, bhc[ni], acc[ni]);
        }
        if (kt < 15) {
            #pragma unroll
            for (int ni = 0; ni < 4; ++ni) { bhc[ni] = bhn[ni]; blc[ni] = bln[ni]; }
        }
        a0 = na0; a1 = na1;
    }
    int cl = lane & 15, rq = (lane >> 4) * 4;
    #pragma unroll
    for (int ni = 0; ni < 4; ++ni) {
        int csub = ni * 16 + cl;
        #pragma unroll
        for (int r = 0; r < 4; ++r)
            outp[(orow + rq + r) * 64 + csub] = acc[ni][r];
    }
}

// ---------------------------------------------------------------
// attn_fused3: grid (32 bh, 16 rblk).  (unchanged)
// ---------------------------------------------------------------
__global__ __launch_bounds__(256) void attn_fused3(const float* __restrict__ qsel,
                                                   const float* __restrict__ ksel,
                                                   const float* __restrict__ vsel,
                                                   const float* __restrict__ sv,
                                                   float* __restrict__ delta) {
    int bh = blockIdx.x;
    int rblk = blockIdx.y;
    __shared__ float Kt[64 * 256];       // 64 KB; E[16][256] aliases after QK
    __shared__ float Qs[16 * 64];        // 4 KB
    __shared__ float umS[16], izS[16];
    int tid = threadIdx.x;
    {
        int j = tid;
        const float4* kp4 = (const float4*)(ksel + ((size_t)bh * TK + j) * 64);
        #pragma unroll
        for (int d4 = 0; d4 < 16; ++d4) {
            float4 kv = kp4[d4];
            Kt[(d4 * 4 + 0) * 256 + j] = kv.x;
            Kt[(d4 * 4 + 1) * 256 + j] = kv.y;
            Kt[(d4 * 4 + 2) * 256 + j] = kv.z;
            Kt[(d4 * 4 + 3) * 256 + j] = kv.w;
        }
    }
    for (int idx = tid; idx < 16 * 64; idx += 256)
        Qs[idx] = qsel[((size_t)bh * TK + rblk * 16) * 64 + idx];
    __syncthreads();

    int wave = tid >> 6, lane = tid & 63;
    int iw0 = wave * 4;
    float e[4][4];
    #pragma unroll
    for (int r = 0; r < 4; ++r)
        #pragma unroll
        for (int t = 0; t < 4; ++t) e[r][t] = 0.f;
    #pragma unroll 8
    for (int d = 0; d < 64; ++d) {
        float4 kv = *(const float4*)&Kt[d * 256 + 4 * lane];
        #pragma unroll
        for (int r = 0; r < 4; ++r) {
            float qd = Qs[(iw0 + r) * 64 + d];
            e[r][0] += qd * kv.x; e[r][1] += qd * kv.y;
            e[r][2] += qd * kv.z; e[r][3] += qd * kv.w;
        }
    }
    #pragma unroll
    for (int r = 0; r < 4; ++r) {
        float s0 = e[r][0] * 0.125f, s1 = e[r][1] * 0.125f;
        float s2 = e[r][2] * 0.125f, s3 = e[r][3] * 0.125f;
        float mx = fmaxf(fmaxf(s0, s1), fmaxf(s2, s3));
        #pragma unroll
        for (int off = 32; off; off >>= 1) mx = fmaxf(mx, __shfl_xor(mx, off, 64));
        mx = fmaxf(mx, 0.0f);
        float e0 = __expf(s0 - mx), e1 = __expf(s1 - mx);
        float e2 = __expf(s2 - mx), e3 = __expf(s3 - mx);
        float zs = e0 + e1 + e2 + e3;
        #pragma unroll
        for (int off = 32; off; off >>= 1) zs += __shfl_xor(zs, off, 64);
        if (lane == 0) {
            float em = __expf(-mx);
            umS[iw0 + r] = em;
            izS[iw0 + r] = 1.0f / ((float)(Nseq - TK) * em + zs);
        }
        e[r][0] = e0; e[r][1] = e1; e[r][2] = e2; e[r][3] = e3;
    }
    __syncthreads();
    float* E = Kt;
    #pragma unroll
    for (int r = 0; r < 4; ++r)
        *(float4*)&E[(iw0 + r) * 256 + 4 * lane] = (float4){e[r][0], e[r][1], e[r][2], e[r][3]};
    __syncthreads();

    const float* vbase = vsel + (size_t)bh * TK * 64 + lane;
    float ssel = 0.f;
    float acc[4];
    #pragma unroll
    for (int r = 0; r < 4; ++r) acc[r] = 0.f;
    #pragma unroll 4
    for (int j = 0; j < TK; ++j) {
        float v = vbase[j * 64];
        ssel += v;
        #pragma unroll
        for (int r = 0; r < 4; ++r)
            acc[r] += E[(iw0 + r) * 256 + j] * v;
    }
    float svd = sv[bh * 64 + lane];
    float sadj = svd - ssel;
    float uval = svd * (1.0f / Nseq);
    #pragma unroll
    for (int r = 0; r < 4; ++r) {
        int i = rblk * 16 + iw0 + r;
        float outv = (umS[iw0 + r] * sadj + acc[r]) * izS[iw0 + r];
        delta[((size_t)bh * TK + i) * 64 + lane] = outv - uval;
    }
}

// ---------------------------------------------------------------
// deltamm_ub: 64-row tiles.  (unchanged)
// ---------------------------------------------------------------
__global__ __launch_bounds__(256) void deltamm_ub(const float* __restrict__ delta,
                                                  const float* __restrict__ w_out,
                                                  const float* __restrict__ b_out,
                                                  const float* __restrict__ sv,
                                                  float* __restrict__ deltaout,
                                                  float* __restrict__ ubase) {
    int bid = blockIdx.x;
    int tid = threadIdx.x;
    if (bid < 512) {
        int bh = bid >> 4, sub = bid & 15;
        int rh = sub >> 2, ct = sub & 3;
        int h = bh & 7;
        __shared__ float As[64][65];
        __shared__ float Ws[64][132];
        for (int idx = tid; idx < 64 * 64; idx += 256) {
            int row = idx >> 6, k = idx & 63;
            As[row][k] = delta[((size_t)bh * TK + rh * 64 + row) * 64 + k];
        }
        for (int idx = tid; idx < 64 * 128; idx += 256) {
            int k = idx >> 7, c = idx & 127;
            Ws[k][c] = w_out[(size_t)(h * 64 + k) * 512 + ct * 128 + c];
        }
        __syncthreads();
        int tx = tid & 15, ty = tid >> 4;
        float acc[4][8];
        #pragma unroll
        for (int r = 0; r < 4; ++r)
            #pragma unroll
            for (int c = 0; c < 8; ++c) acc[r][c] = 0.f;
        for (int k = 0; k < 64; ++k) {
            float a[4], bv[8];
            #pragma unroll
            for (int r = 0; r < 4; ++r) a[r] = As[ty * 4 + r][k];
            #pragma unroll
            for (int cc = 0; cc < 4; ++cc) {
                bv[cc]     = Ws[k][tx * 4 + cc];
                bv[4 + cc] = Ws[k][64 + tx * 4 + cc];
            }
            #pragma unroll
            for (int r = 0; r < 4; ++r)
                #pragma unroll
                for (int c = 0; c < 8; ++c) acc[r][c] += a[r] * bv[c];
        }
        #pragma unroll
        for (int r = 0; r < 4; ++r) {
            size_t ro = ((size_t)bh * TK + rh * 64 + ty * 4 + r) * 512 + ct * 128;
            #pragma unroll
            for (int cc = 0; cc < 4; ++cc) {
                deltaout[ro + tx * 4 + cc]      = acc[r][cc];
                deltaout[ro + 64 + tx * 4 + cc] = acc[r][4 + cc];
            }
        }
    } else {
        int r2 = bid - 512;
        int b = r2 >> 3;
        int c0 = (r2 & 7) * 64;
        int c = tid & 63, kg = tid >> 6;
        float s = 0.f;
        for (int k = kg * 128; k < kg * 128 + 128; ++k) {
            float hu = sv[(b * 8 + (k >> 6)) * 64 + (k & 63)] * (1.0f / Nseq);
            s += hu * w_out[(size_t)k * 512 + c0 + c];
        }
        __shared__ float red[4][64];
        red[kg][c] = s;
        __syncthreads();
        if (tid < 64)
            ubase[b * 512 + c0 + c] = red[0][c] + red[1][c] + red[2][c] + red[3][c] + b_out[c0 + c];
    }
}

// ---------------------------------------------------------------
// compose: out = ubase + gathered deltaout.  (unchanged)
// ---------------------------------------------------------------
__global__ __launch_bounds__(256) void compose(const float* __restrict__ ubase,
                                               const int* __restrict__ rankmap,
                                               const float* __restrict__ deltaout,
                                               float* __restrict__ out) {
    int r0 = blockIdx.x * 4;
    int b = r0 >> 11;
    int tid = threadIdx.x;
    float u0 = ubase[b * 512 + tid];
    float u1 = ubase[b * 512 + 256 + tid];
    for (int rr = 0; rr < 4; ++rr) {
        int i = (r0 + rr) & 2047;
        float a0 = u0, a1 = u1;
        #pragma unroll
        for (int h = 0; h < 8; ++h) {
            int rk = rankmap[(size_t)(b * 8 + h) * Nseq + i];
            if (rk >= 0) {
                const float* dp = deltaout + ((size_t)(b * 8 + h) * TK + rk) * 512;
                a0 += dp[tid];
                a1 += dp[256 + tid];
            }
        }
        float* op = out + ((size_t)b * Nseq + i) * 512;
        op[tid] = a0;
        op[256 + tid] = a1;
    }
}

extern "C" void kernel_launch(void* const* d_in, const int* in_sizes, int n_in,
                              void* d_out, int out_size, void* d_ws, size_t ws_size,
                              hipStream_t stream) {
    const float* x     = (const float*)d_in[0];
    const float* w_qkv = (const float*)d_in[1];
    const float* w_out = (const float*)d_in[2];
    const float* b_out = (const float*)d_in[3];
    float* out = (float*)d_out;

    float* ws = (float*)d_ws;
    float* xpart   = ws;                            // 262144 f
    float* spart   = xpart + 262144;                // 98304 f
    float* sv      = spart + 98304;                 // 2048 f
    float* rvec    = sv + 2048;                     // 16384 f
    float* cvec    = rvec + 16384;
    float* rsc     = cvec + 16384;                  // 65536 f
    float* csc     = rsc + 65536;
    int*   ridx    = (int*)(csc + 65536);           // 8192 i
    int*   cidx    = ridx + 8192;
    int*   rankmap = cidx + 8192;                   // 65536 i
    float* ubase   = (float*)(rankmap + 65536);     // 2048 f
    bf16x8* Bp_hi  = (bf16x8*)(ubase + 2048);       // 393216 f
    bf16x8* Bp_lo  = (bf16x8*)((float*)Bp_hi + 393216);
    float* qsel    = (float*)Bp_lo + 393216;        // 524288 f
    float* ksel    = qsel + 524288;
    float* vsel    = ksel + 524288;
    float* delta   = vsel + 524288;                 // 524288 f
    float* deltaout = delta + 524288;               // 4194304 f

    // 1. x column partial sums
    xprep<<<512, 256, 0, stream>>>(x, xpart);
    // 2. partial stats GEMM + W fragment packing
    statsAW<<<768, 256, 0, stream>>>(xpart, w_qkv, spart, Bp_hi, Bp_lo);
    // 3. finalize qm/km/sv + folded score vectors
    statsB<<<dim3(BH, 2), 256, 0, stream>>>(spart, w_qkv, sv, rvec, cvec);
    // 4. rank-1 scores, single pass over x
    score4_kernel<<<dim3(Bsz, 128), 128, 0, stream>>>(x, rvec, cvec, rsc, csc);
    // 5. top-256 + rankmap via radix-select (shfl scans)
    topk5<<<BH * 2, 256, 0, stream>>>(rsc, csc, ridx, cidx, rankmap);
    // 6. barrier-free gather-GEMM (B prefetch)
    selgemm4<<<dim3(4, 3, BH), 256, 0, stream>>>(x, ridx, cidx, Bp_hi, Bp_lo, qsel, ksel, vsel);
    // 7. fused attention -> compact delta
    attn_fused3<<<dim3(BH, 16), 256, 0, stream>>>(qsel, ksel, vsel, sv, delta);
    // 8. delta @ w_out + uniform base rows
    deltamm_ub<<<544, 256, 0, stream>>>(delta, w_out, b_out, sv, deltaout, ubase);
    // 9. compose final output
    compose<<<Bsz * Nseq / 4, 256, 0, stream>>>(ubase, rankmap, deltaout, out);
}

// Round 12
// 164.053 us; speedup vs baseline: 3.0123x; 1.0493x over previous
//
#include <hip/hip_runtime.h>
#include <math.h>

#define Bsz 4
#define Nseq 2048
#define Cdim 512
#define Hn 8
#define Dh 64
#define TK 256
#define BH (Bsz*Hn)          // 32
#define QKVC 1536

typedef __attribute__((ext_vector_type(8))) short bf16x8;
typedef __attribute__((ext_vector_type(4))) float f32x4;

__device__ __forceinline__ unsigned short f2bf(float x) {
    unsigned u = __float_as_uint(x);
    unsigned r = (u + 0x7fffu + ((u >> 16) & 1u)) >> 16;   // round-to-nearest-even
    return (unsigned short)r;
}
__device__ __forceinline__ float bf2f(unsigned short h) {
    return __uint_as_float((unsigned)h << 16);
}
__device__ __forceinline__ f32x4 mfma16(bf16x8 a, bf16x8 b, f32x4 c) {
    return __builtin_amdgcn_mfma_f32_16x16x32_bf16(a, b, c, 0, 0, 0);
}

// ---------------------------------------------------------------
// xprep: partial column sums of x, 16-row chunks. grid 512.
// ---------------------------------------------------------------
__global__ __launch_bounds__(256) void xprep(const float* __restrict__ x,
                                             float* __restrict__ xpart) {
    int r = blockIdx.x;                  // 0..511
    int tid = threadIdx.x;
    int b = r >> 7, rc = r & 127;
    const float* xp = x + ((size_t)b * Nseq + rc * 16) * Cdim;
    float s0 = 0.f, s1 = 0.f;
    #pragma unroll 4
    for (int rr = 0; rr < 16; ++rr) {
        s0 += xp[rr * Cdim + tid];
        s1 += xp[rr * Cdim + 256 + tid];
    }
    xpart[((size_t)b * 128 + rc) * Cdim + tid] = s0;
    xpart[((size_t)b * 128 + rc) * Cdim + 256 + tid] = s1;
}

// ---------------------------------------------------------------
// statsAW: block-range fusion.
//  blocks [0,384):   statsA partial stats GEMM
//  blocks [384,768): W-pack w_qkv -> hi/lo bf16 fragments
// ---------------------------------------------------------------
__global__ __launch_bounds__(256) void statsAW(const float* __restrict__ xpart,
                                               const float* __restrict__ w_qkv,
                                               float* __restrict__ spart,
                                               bf16x8* __restrict__ hi,
                                               bf16x8* __restrict__ lo) {
    int bid = blockIdx.x;
    int t = threadIdx.x;
    if (bid < 384) {
        int b = bid & 3, kc = (bid >> 2) & 15, nb = bid >> 6;
        __shared__ float xr[8][32];
        __shared__ float xs[32];
        int i = t & 31, g = t >> 5;
        float s = 0.f;
        #pragma unroll 4
        for (int j = 0; j < 16; ++j)
            s += xpart[((size_t)b * 128 + g * 16 + j) * Cdim + kc * 32 + i];
        xr[g][i] = s;
        __syncthreads();
        if (t < 32) {
            float v = 0.f;
            #pragma unroll
            for (int gg = 0; gg < 8; ++gg) v += xr[gg][t];
            xs[t] = v;
        }
        __syncthreads();
        float a0 = 0.f;
        const float* wbase = w_qkv + (size_t)(kc * 32) * QKVC + nb * 256 + t;
        #pragma unroll 4
        for (int i2 = 0; i2 < 32; ++i2)
            a0 += xs[i2] * wbase[(size_t)i2 * QKVC];
        spart[(size_t)(b * 16 + kc) * QKVC + nb * 256 + t] = a0;
    } else {
        int u = bid - 384;
        int nt = u >> 2;
        int kt = (u & 3) * 4 + (t >> 6);
        int lane = t & 63;
        int c = nt * 16 + (lane & 15);
        int kbase = kt * 32 + (lane >> 4) * 8;
        bf16x8 h, l;
        #pragma unroll
        for (int j = 0; j < 8; ++j) {
            float v = w_qkv[(size_t)(kbase + j) * QKVC + c];
            unsigned short hv = f2bf(v);
            h[j] = (short)hv;
            l[j] = (short)f2bf(v - bf2f(hv));
        }
        int idx = (nt * 16 + kt) * 64 + lane;
        hi[idx] = h;
        lo[idx] = l;
    }
}

// ---------------------------------------------------------------
// statsB: finalize qm/km/sv from spart, then rvec/cvec. grid (32, 2).
// ---------------------------------------------------------------
__global__ __launch_bounds__(256) void statsB(const float* __restrict__ spart,
                                              const float* __restrict__ w_qkv,
                                              float* __restrict__ sv,
                                              float* __restrict__ rvec,
                                              float* __restrict__ cvec) {
    int bh = blockIdx.x, cb = blockIdx.y;
    int b = bh >> 3, h = bh & 7;
    __shared__ float qm[64], km[64];
    int t = threadIdx.x;
    if (t < 192) {
        int which = t >> 6, d = t & 63;
        int col = which * 512 + h * 64 + d;
        float s = 0.f;
        #pragma unroll
        for (int kc = 0; kc < 16; ++kc)
            s += spart[(size_t)(b * 16 + kc) * QKVC + col];
        if (which == 0)      qm[d] = s * (1.0f / Nseq);
        else if (which == 1) km[d] = s * (1.0f / Nseq);
        else if (cb == 0)    sv[bh * 64 + d] = s;
    }
    __syncthreads();
    int c = cb * 256 + t;
    const float4* wr = (const float4*)(w_qkv + (size_t)c * QKVC + h * 64);
    const float4* wc = (const float4*)(w_qkv + (size_t)c * QKVC + 512 + h * 64);
    float r = 0.f, cv = 0.f;
    #pragma unroll
    for (int d4 = 0; d4 < 16; ++d4) {
        float4 w1 = wr[d4], w2 = wc[d4];
        float4 k1 = *(const float4*)&km[d4 * 4];
        float4 q1 = *(const float4*)&qm[d4 * 4];
        r  += w1.x * k1.x + w1.y * k1.y + w1.z * k1.z + w1.w * k1.w;
        cv += w2.x * q1.x + w2.y * q1.y + w2.z * q1.z + w2.w * q1.w;
    }
    rvec[(size_t)bh * Cdim + c] = r;
    cvec[(size_t)bh * Cdim + c] = cv;
}

// ---------------------------------------------------------------
// score4: single-pass rank-1 scores.  grid (4 b, 128 rc), 128 threads.
// ---------------------------------------------------------------
__global__ __launch_bounds__(128) void score4_kernel(const float* __restrict__ x,
                                                     const float* __restrict__ rvec,
                                                     const float* __restrict__ cvec,
                                                     float* __restrict__ rsc,
                                                     float* __restrict__ csc) {
    int b = blockIdx.x, rc = blockIdx.y;
    __shared__ float vs[16 * 8 * 68];     // 34.8 KB
    int t = threadIdx.x;
    int r = t >> 3, g = t & 7;

    const float4* xp = (const float4*)(x + ((size_t)b * Nseq + rc * 16 + r) * Cdim + g * 64);
    float4 xr[16];
    #pragma unroll
    for (int j4 = 0; j4 < 16; ++j4) xr[j4] = xp[j4];

    {
        const float4* rp = (const float4*)(rvec + (size_t)b * 8 * Cdim);
        const float4* cp = (const float4*)(cvec + (size_t)b * 8 * Cdim);
        for (int i = t; i < 16 * 128; i += 128) {
            int v = i >> 7, c4 = i & 127;
            float4 val = (v < 8) ? rp[v * 128 + c4] : cp[(v - 8) * 128 + c4];
            int gg = c4 >> 4, j4 = c4 & 15;
            *(float4*)&vs[(v * 8 + gg) * 68 + j4 * 4] = val;
        }
    }
    __syncthreads();

    float acc[16];
    #pragma unroll
    for (int v = 0; v < 16; ++v) acc[v] = 0.f;
    #pragma unroll
    for (int j4 = 0; j4 < 16; ++j4) {
        float4 xv = xr[j4];
        #pragma unroll
        for (int v = 0; v < 16; ++v) {
            float4 wv = *(const float4*)&vs[(v * 8 + g) * 68 + j4 * 4];
            acc[v] += xv.x * wv.x + xv.y * wv.y + xv.z * wv.z + xv.w * wv.w;
        }
    }
    #pragma unroll
    for (int v = 0; v < 16; ++v) {
        float s = acc[v];
        s += __shfl_xor(s, 1, 64);
        s += __shfl_xor(s, 2, 64);
        s += __shfl_xor(s, 4, 64);
        acc[v] = s;
    }
    if (g == 0) {
        int i = rc * 16 + r;
        #pragma unroll
        for (int v = 0; v < 8; ++v) {
            rsc[(size_t)(b * 8 + v) * Nseq + i] = acc[v] * 0.125f;
            csc[(size_t)(b * 8 + v) * Nseq + i] = acc[8 + v] * 0.125f;
        }
    }
}

// ---------------------------------------------------------------
// topk6: radix-select top-256, shfl scans + PER-WAVE histograms
// (4x less LDS-atomic contention on hot buckets; integer-exact,
// outputs bit-identical to topk4/5).  grid 64.
// ---------------------------------------------------------------
__global__ __launch_bounds__(256) void topk6(const float* __restrict__ rsc,
                                             const float* __restrict__ csc,
                                             int* __restrict__ ridx,
                                             int* __restrict__ cidx,
                                             int* __restrict__ rankmap) {
    int selid = blockIdx.x;
    int bh = selid >> 1, which = selid & 1;
    const float* sin = which ? (csc + (size_t)bh * Nseq) : (rsc + (size_t)bh * Nseq);
    __shared__ int hist[4][256];
    __shared__ int wsum[4];
    __shared__ int tieidx[2048];
    __shared__ int sh_D, sh_above, sh_tiecnt;
    int tid = threadIdx.x;
    int lane = tid & 63, wv = tid >> 6;

    unsigned k[8];
    #pragma unroll
    for (int j = 0; j < 8; ++j) {
        unsigned u = __float_as_uint(sin[j * 256 + tid]);
        k[j] = (u & 0x80000000u) ? ~u : (u | 0x80000000u);
    }

    unsigned pref = 0;
    int above = 0;
    for (int level = 3; level >= 0; --level) {
        hist[0][tid] = 0; hist[1][tid] = 0; hist[2][tid] = 0; hist[3][tid] = 0;
        __syncthreads();
        int sh = level * 8;
        #pragma unroll
        for (int j = 0; j < 8; ++j) {
            bool match = (level == 3) || ((k[j] >> (sh + 8)) == pref);
            if (match) atomicAdd(&hist[wv][(k[j] >> sh) & 255], 1);
        }
        __syncthreads();
        int h = hist[0][tid] + hist[1][tid] + hist[2][tid] + hist[3][tid];
        // inclusive suffix scan: intra-wave shfl + wave-total combine
        int v = h;
        #pragma unroll
        for (int off = 1; off < 64; off <<= 1) {
            int tt = __shfl_down(v, off, 64);
            if (lane + off < 64) v += tt;
        }
        if (lane == 0) wsum[wv] = v;
        __syncthreads();
        int add = 0;
        #pragma unroll
        for (int w = 0; w < 4; ++w) if (w > wv) add += wsum[w];
        v += add;
        int Sincl = v, Sexcl = v - h;
        if (above + Sexcl < TK && above + Sincl >= TK) {
            sh_D = tid;
            sh_above = above + Sexcl;
        }
        __syncthreads();
        pref = (pref << 8) | (unsigned)sh_D;
        above = sh_above;
        __syncthreads();   // protect wsum/sh_D/hist reuse next level
    }
    unsigned T = pref;          // exact 256th-largest key
    int rem = TK - above;

    if (tid == 0) sh_tiecnt = 0;
    __syncthreads();
    int cnt = 0;
    #pragma unroll
    for (int j = 0; j < 8; ++j) {
        if (k[j] > T) ++cnt;
        if (k[j] == T) {
            int p = atomicAdd(&sh_tiecnt, 1);
            tieidx[p] = j * 256 + tid;
        }
    }
    // exclusive forward prefix scan of cnt (shfl + wave combine)
    int v = cnt;
    #pragma unroll
    for (int off = 1; off < 64; off <<= 1) {
        int tt = __shfl_up(v, off, 64);
        if (lane >= off) v += tt;
    }
    if (lane == 63) wsum[wv] = v;
    __syncthreads();            // also fences tie atomics + tieidx writes
    int add = 0;
    #pragma unroll
    for (int w = 0; w < 4; ++w) if (w < wv) add += wsum[w];
    int base = v + add - cnt;   // exclusive prefix of >T counts
    int tc = sh_tiecnt;
    int* outp = which ? (cidx + bh * TK) : (ridx + bh * TK);
    #pragma unroll
    for (int j = 0; j < 8; ++j) {
        int i = j * 256 + tid;
        int r = -1;
        if (k[j] > T) {
            r = base++;
        } else if (k[j] == T) {
            int rk = 0;
            for (int t2 = 0; t2 < tc; ++t2) rk += (tieidx[t2] < i) ? 1 : 0;
            if (rk < rem) r = above + rk;
        }
        if (r >= 0) outp[r] = i;
        if (which == 0) rankmap[(size_t)bh * Nseq + i] = r;
    }
}

// ---------------------------------------------------------------
// selgemm4: barrier-free gather-GEMM, NI=4, 1-deep B prefetch.
// grid (4 mq, 3 part, 32 bh).  (unchanged round 11)
// ---------------------------------------------------------------
__global__ __launch_bounds__(256) void selgemm4(const float* __restrict__ x,
                                                const int* __restrict__ ridx,
                                                const int* __restrict__ cidx,
                                                const bf16x8* __restrict__ Bph,
                                                const bf16x8* __restrict__ Bpl,
                                                float* __restrict__ qsel,
                                                float* __restrict__ ksel,
                                                float* __restrict__ vsel) {
    int mq = blockIdx.x, part = blockIdx.y, bh = blockIdx.z;
    int b = bh >> 3, h = bh & 7;
    int tid = threadIdx.x;
    int wv = tid >> 6, lane = tid & 63;
    const int* idxp = (part == 0 ? ridx : cidx) + bh * TK + mq * 64 + wv * 16;
    int row = idxp[lane & 15];
    const float* ap = x + ((size_t)b * Nseq + row) * Cdim + (lane >> 4) * 8;
    size_t orow = (size_t)bh * TK + mq * 64 + wv * 16;
    int nt0 = (part == 0) ? (h * 4) : (part == 1 ? (32 + h * 4) : (64 + h * 4));
    float* outp = (part == 0) ? qsel : (part == 1 ? ksel : vsel);

    f32x4 acc[4];
    #pragma unroll
    for (int i = 0; i < 4; ++i) acc[i] = (f32x4){0.f, 0.f, 0.f, 0.f};

    bf16x8 bhc[4], blc[4];
    #pragma unroll
    for (int ni = 0; ni < 4; ++ni) {
        bhc[ni] = Bph[((size_t)(nt0 + ni) * 16 + 0) * 64 + lane];
        blc[ni] = Bpl[((size_t)(nt0 + ni) * 16 + 0) * 64 + lane];
    }
    float4 a0 = *(const float4*)ap;
    float4 a1 = *(const float4*)(ap + 4);
    #pragma unroll 2
    for (int kt = 0; kt < 16; ++kt) {
        float4 na0 = a0, na1 = a1;
        bf16x8 bhn[4], bln[4];
        if (kt < 15) {
            na0 = *(const float4*)(ap + (kt + 1) * 32);
            na1 = *(const float4*)(ap + (kt + 1) * 32 + 4);
            #pragma unroll
            for (int ni = 0; ni < 4; ++ni) {
                bhn[ni] = Bph[((size_t)(nt0 + ni) * 16 + (kt + 1)) * 64 + lane];
                bln[ni] = Bpl[((size_t)(nt0 + ni) * 16 + (kt + 1)) * 64 + lane];
            }
        }
        float vv[8] = {a0.x, a0.y, a0.z, a0.w, a1.x, a1.y, a1.z, a1.w};
        bf16x8 ah, al;
        #pragma unroll
        for (int j = 0; j < 8; ++j) {
            unsigned short hv = f2bf(vv[j]);
            ah[j] = (short)hv;
            al[j] = (short)f2bf(vv[j] - bf2f(hv));
        }
        #pragma unroll
        for (int ni = 0; ni < 4; ++ni) {
            acc[ni] = mfma16(ah, bhc[ni], acc[ni]);
            acc[ni] = mfma16(ah, blc[ni], acc[ni]);
            acc[ni] = mfma16(al, bhc[ni], acc[ni]);
        }
        if (kt < 15) {
            #pragma unroll
            for (int ni = 0; ni < 4; ++ni) { bhc[ni] = bhn[ni]; blc[ni] = bln[ni]; }
        }
        a0 = na0; a1 = na1;
    }
    int cl = lane & 15, rq = (lane >> 4) * 4;
    #pragma unroll
    for (int ni = 0; ni < 4; ++ni) {
        int csub = ni * 16 + cl;
        #pragma unroll
        for (int r = 0; r < 4; ++r)
            outp[(orow + rq + r) * 64 + csub] = acc[ni][r];
    }
}

// ---------------------------------------------------------------
// attn_fused4: grid (32 bh, 16 rblk).  PV loop unroll 16 -> 16
// outstanding V loads (was 4); FP chain order unchanged.
// ---------------------------------------------------------------
__global__ __launch_bounds__(256) void attn_fused4(const float* __restrict__ qsel,
                                                   const float* __restrict__ ksel,
                                                   const float* __restrict__ vsel,
                                                   const float* __restrict__ sv,
                                                   float* __restrict__ delta) {
    int bh = blockIdx.x;
    int rblk = blockIdx.y;
    __shared__ float Kt[64 * 256];       // 64 KB; E[16][256] aliases after QK
    __shared__ float Qs[16 * 64];        // 4 KB
    __shared__ float umS[16], izS[16];
    int tid = threadIdx.x;
    {
        int j = tid;
        const float4* kp4 = (const float4*)(ksel + ((size_t)bh * TK + j) * 64);
        #pragma unroll
        for (int d4 = 0; d4 < 16; ++d4) {
            float4 kv = kp4[d4];
            Kt[(d4 * 4 + 0) * 256 + j] = kv.x;
            Kt[(d4 * 4 + 1) * 256 + j] = kv.y;
            Kt[(d4 * 4 + 2) * 256 + j] = kv.z;
            Kt[(d4 * 4 + 3) * 256 + j] = kv.w;
        }
    }
    for (int idx = tid; idx < 16 * 64; idx += 256)
        Qs[idx] = qsel[((size_t)bh * TK + rblk * 16) * 64 + idx];
    __syncthreads();

    int wave = tid >> 6, lane = tid & 63;
    int iw0 = wave * 4;
    float e[4][4];
    #pragma unroll
    for (int r = 0; r < 4; ++r)
        #pragma unroll
        for (int t = 0; t < 4; ++t) e[r][t] = 0.f;
    #pragma unroll 8
    for (int d = 0; d < 64; ++d) {
        float4 kv = *(const float4*)&Kt[d * 256 + 4 * lane];
        #pragma unroll
        for (int r = 0; r < 4; ++r) {
            float qd = Qs[(iw0 + r) * 64 + d];
            e[r][0] += qd * kv.x; e[r][1] += qd * kv.y;
            e[r][2] += qd * kv.z; e[r][3] += qd * kv.w;
        }
    }
    #pragma unroll
    for (int r = 0; r < 4; ++r) {
        float s0 = e[r][0] * 0.125f, s1 = e[r][1] * 0.125f;
        float s2 = e[r][2] * 0.125f, s3 = e[r][3] * 0.125f;
        float mx = fmaxf(fmaxf(s0, s1), fmaxf(s2, s3));
        #pragma unroll
        for (int off = 32; off; off >>= 1) mx = fmaxf(mx, __shfl_xor(mx, off, 64));
        mx = fmaxf(mx, 0.0f);
        float e0 = __expf(s0 - mx), e1 = __expf(s1 - mx);
        float e2 = __expf(s2 - mx), e3 = __expf(s3 - mx);
        float zs = e0 + e1 + e2 + e3;
        #pragma unroll
        for (int off = 32; off; off >>= 1) zs += __shfl_xor(zs, off, 64);
        if (lane == 0) {
            float em = __expf(-mx);
            umS[iw0 + r] = em;
            izS[iw0 + r] = 1.0f / ((float)(Nseq - TK) * em + zs);
        }
        e[r][0] = e0; e[r][1] = e1; e[r][2] = e2; e[r][3] = e3;
    }
    __syncthreads();
    float* E = Kt;
    #pragma unroll
    for (int r = 0; r < 4; ++r)
        *(float4*)&E[(iw0 + r) * 256 + 4 * lane] = (float4){e[r][0], e[r][1], e[r][2], e[r][3]};
    __syncthreads();

    const float* vbase = vsel + (size_t)bh * TK * 64 + lane;
    float ssel = 0.f;
    float acc[4];
    #pragma unroll
    for (int r = 0; r < 4; ++r) acc[r] = 0.f;
    #pragma unroll 16
    for (int j = 0; j < TK; ++j) {
        float v = vbase[j * 64];
        ssel += v;
        #pragma unroll
        for (int r = 0; r < 4; ++r)
            acc[r] += E[(iw0 + r) * 256 + j] * v;
    }
    float svd = sv[bh * 64 + lane];
    float sadj = svd - ssel;
    float uval = svd * (1.0f / Nseq);
    #pragma unroll
    for (int r = 0; r < 4; ++r) {
        int i = rblk * 16 + iw0 + r;
        float outv = (umS[iw0 + r] * sadj + acc[r]) * izS[iw0 + r];
        delta[((size_t)bh * TK + i) * 64 + lane] = outv - uval;
    }
}

// ---------------------------------------------------------------
// deltamm_ub: 64-row tiles.  (unchanged)
// ---------------------------------------------------------------
__global__ __launch_bounds__(256) void deltamm_ub(const float* __restrict__ delta,
                                                  const float* __restrict__ w_out,
                                                  const float* __restrict__ b_out,
                                                  const float* __restrict__ sv,
                                                  float* __restrict__ deltaout,
                                                  float* __restrict__ ubase) {
    int bid = blockIdx.x;
    int tid = threadIdx.x;
    if (bid < 512) {
        int bh = bid >> 4, sub = bid & 15;
        int rh = sub >> 2, ct = sub & 3;
        int h = bh & 7;
        __shared__ float As[64][65];
        __shared__ float Ws[64][132];
        for (int idx = tid; idx < 64 * 64; idx += 256) {
            int row = idx >> 6, k = idx & 63;
            As[row][k] = delta[((size_t)bh * TK + rh * 64 + row) * 64 + k];
        }
        for (int idx = tid; idx < 64 * 128; idx += 256) {
            int k = idx >> 7, c = idx & 127;
            Ws[k][c] = w_out[(size_t)(h * 64 + k) * 512 + ct * 128 + c];
        }
        __syncthreads();
        int tx = tid & 15, ty = tid >> 4;
        float acc[4][8];
        #pragma unroll
        for (int r = 0; r < 4; ++r)
            #pragma unroll
            for (int c = 0; c < 8; ++c) acc[r][c] = 0.f;
        for (int k = 0; k < 64; ++k) {
            float a[4], bv[8];
            #pragma unroll
            for (int r = 0; r < 4; ++r) a[r] = As[ty * 4 + r][k];
            #pragma unroll
            for (int cc = 0; cc < 4; ++cc) {
                bv[cc]     = Ws[k][tx * 4 + cc];
                bv[4 + cc] = Ws[k][64 + tx * 4 + cc];
            }
            #pragma unroll
            for (int r = 0; r < 4; ++r)
                #pragma unroll
                for (int c = 0; c < 8; ++c) acc[r][c] += a[r] * bv[c];
        }
        #pragma unroll
        for (int r = 0; r < 4; ++r) {
            size_t ro = ((size_t)bh * TK + rh * 64 + ty * 4 + r) * 512 + ct * 128;
            #pragma unroll
            for (int cc = 0; cc < 4; ++cc) {
                deltaout[ro + tx * 4 + cc]      = acc[r][cc];
                deltaout[ro + 64 + tx * 4 + cc] = acc[r][4 + cc];
            }
        }
    } else {
        int r2 = bid - 512;
        int b = r2 >> 3;
        int c0 = (r2 & 7) * 64;
        int c = tid & 63, kg = tid >> 6;
        float s = 0.f;
        for (int k = kg * 128; k < kg * 128 + 128; ++k) {
            float hu = sv[(b * 8 + (k >> 6)) * 64 + (k & 63)] * (1.0f / Nseq);
            s += hu * w_out[(size_t)k * 512 + c0 + c];
        }
        __shared__ float red[4][64];
        red[kg][c] = s;
        __syncthreads();
        if (tid < 64)
            ubase[b * 512 + c0 + c] = red[0][c] + red[1][c] + red[2][c] + red[3][c] + b_out[c0 + c];
    }
}

// ---------------------------------------------------------------
// compose2: rankmap preloaded into registers before gathers.
// ---------------------------------------------------------------
__global__ __launch_bounds__(256) void compose2(const float* __restrict__ ubase,
                                                const int* __restrict__ rankmap,
                                                const float* __restrict__ deltaout,
                                                float* __restrict__ out) {
    int r0 = blockIdx.x * 4;
    int b = r0 >> 11;
    int tid = threadIdx.x;
    float u0 = ubase[b * 512 + tid];
    float u1 = ubase[b * 512 + 256 + tid];
    for (int rr = 0; rr < 4; ++rr) {
        int i = (r0 + rr) & 2047;
        int rk[8];
        #pragma unroll
        for (int h = 0; h < 8; ++h)
            rk[h] = rankmap[(size_t)(b * 8 + h) * Nseq + i];
        float a0 = u0, a1 = u1;
        #pragma unroll
        for (int h = 0; h < 8; ++h) {
            if (rk[h] >= 0) {
                const float* dp = deltaout + ((size_t)(b * 8 + h) * TK + rk[h]) * 512;
                a0 += dp[tid];
                a1 += dp[256 + tid];
            }
        }
        float* op = out + ((size_t)b * Nseq + i) * 512;
        op[tid] = a0;
        op[256 + tid] = a1;
    }
}

extern "C" void kernel_launch(void* const* d_in, const int* in_sizes, int n_in,
                              void* d_out, int out_size, void* d_ws, size_t ws_size,
                              hipStream_t stream) {
    const float* x     = (const float*)d_in[0];
    const float* w_qkv = (const float*)d_in[1];
    const float* w_out = (const float*)d_in[2];
    const float* b_out = (const float*)d_in[3];
    float* out = (float*)d_out;

    float* ws = (float*)d_ws;
    float* xpart   = ws;                            // 262144 f
    float* spart   = xpart + 262144;                // 98304 f
    float* sv      = spart + 98304;                 // 2048 f
    float* rvec    = sv + 2048;                     // 16384 f
    float* cvec    = rvec + 16384;
    float* rsc     = cvec + 16384;                  // 65536 f
    float* csc     = rsc + 65536;
    int*   ridx    = (int*)(csc + 65536);           // 8192 i
    int*   cidx    = ridx + 8192;
    int*   rankmap = cidx + 8192;                   // 65536 i
    float* ubase   = (float*)(rankmap + 65536);     // 2048 f
    bf16x8* Bp_hi  = (bf16x8*)(ubase + 2048);       // 393216 f
    bf16x8* Bp_lo  = (bf16x8*)((float*)Bp_hi + 393216);
    float* qsel    = (float*)Bp_lo + 393216;        // 524288 f
    float* ksel    = qsel + 524288;
    float* vsel    = ksel + 524288;
    float* delta   = vsel + 524288;                 // 524288 f
    float* deltaout = delta + 524288;               // 4194304 f

    // 1. x column partial sums
    xprep<<<512, 256, 0, stream>>>(x, xpart);
    // 2. partial stats GEMM + W fragment packing
    statsAW<<<768, 256, 0, stream>>>(xpart, w_qkv, spart, Bp_hi, Bp_lo);
    // 3. finalize qm/km/sv + folded score vectors
    statsB<<<dim3(BH, 2), 256, 0, stream>>>(spart, w_qkv, sv, rvec, cvec);
    // 4. rank-1 scores, single pass over x
    score4_kernel<<<dim3(Bsz, 128), 128, 0, stream>>>(x, rvec, cvec, rsc, csc);
    // 5. top-256 + rankmap via radix-select (per-wave hist, shfl scans)
    topk6<<<BH * 2, 256, 0, stream>>>(rsc, csc, ridx, cidx, rankmap);
    // 6. barrier-free gather-GEMM (B prefetch)
    selgemm4<<<dim3(4, 3, BH), 256, 0, stream>>>(x, ridx, cidx, Bp_hi, Bp_lo, qsel, ksel, vsel);
    // 7. fused attention (deep-ILP PV) -> compact delta
    attn_fused4<<<dim3(BH, 16), 256, 0, stream>>>(qsel, ksel, vsel, sv, delta);
    // 8. delta @ w_out + uniform base rows
    deltamm_ub<<<544, 256, 0, stream>>>(delta, w_out, b_out, sv, deltaout, ubase);
    // 9. compose final output
    compose2<<<Bsz * Nseq / 4, 256, 0, stream>>>(ubase, rankmap, deltaout, out);
}

// Round 13
// 162.214 us; speedup vs baseline: 3.0465x; 1.0113x over previous
//
#include <hip/hip_runtime.h>
#include <math.h>

#define Bsz 4
#define Nseq 2048
#define Cdim 512
#define Hn 8
#define Dh 64
#define TK 256
#define BH (Bsz*Hn)          // 32
#define QKVC 1536

typedef __attribute__((ext_vector_type(8))) short bf16x8;
typedef __attribute__((ext_vector_type(4))) float f32x4;

__device__ __forceinline__ unsigned short f2bf(float x) {
    unsigned u = __float_as_uint(x);
    unsigned r = (u + 0x7fffu + ((u >> 16) & 1u)) >> 16;   // round-to-nearest-even
    return (unsigned short)r;
}
__device__ __forceinline__ float bf2f(unsigned short h) {
    return __uint_as_float((unsigned)h << 16);
}
__device__ __forceinline__ f32x4 mfma16(bf16x8 a, bf16x8 b, f32x4 c) {
    return __builtin_amdgcn_mfma_f32_16x16x32_bf16(a, b, c, 0, 0, 0);
}

// ---------------------------------------------------------------
// xprep: partial column sums of x, 16-row chunks. grid 512.
// Full unroll: 32 outstanding loads; FP chains keep order.
// ---------------------------------------------------------------
__global__ __launch_bounds__(256) void xprep(const float* __restrict__ x,
                                             float* __restrict__ xpart) {
    int r = blockIdx.x;                  // 0..511
    int tid = threadIdx.x;
    int b = r >> 7, rc = r & 127;
    const float* xp = x + ((size_t)b * Nseq + rc * 16) * Cdim;
    float v0[16], v1[16];
    #pragma unroll
    for (int rr = 0; rr < 16; ++rr) {
        v0[rr] = xp[rr * Cdim + tid];
        v1[rr] = xp[rr * Cdim + 256 + tid];
    }
    float s0 = 0.f, s1 = 0.f;
    #pragma unroll
    for (int rr = 0; rr < 16; ++rr) { s0 += v0[rr]; s1 += v1[rr]; }
    xpart[((size_t)b * 128 + rc) * Cdim + tid] = s0;
    xpart[((size_t)b * 128 + rc) * Cdim + 256 + tid] = s1;
}

// ---------------------------------------------------------------
// statsAW: block-range fusion.
//  blocks [0,384):   statsA partial stats GEMM (full-unroll chains)
//  blocks [384,768): W-pack w_qkv -> hi/lo bf16 fragments
// ---------------------------------------------------------------
__global__ __launch_bounds__(256) void statsAW(const float* __restrict__ xpart,
                                               const float* __restrict__ w_qkv,
                                               float* __restrict__ spart,
                                               bf16x8* __restrict__ hi,
                                               bf16x8* __restrict__ lo) {
    int bid = blockIdx.x;
    int t = threadIdx.x;
    if (bid < 384) {
        int b = bid & 3, kc = (bid >> 2) & 15, nb = bid >> 6;
        __shared__ float xr[8][32];
        __shared__ float xs[32];
        int i = t & 31, g = t >> 5;
        float xv[16];
        #pragma unroll
        for (int j = 0; j < 16; ++j)
            xv[j] = xpart[((size_t)b * 128 + g * 16 + j) * Cdim + kc * 32 + i];
        float s = 0.f;
        #pragma unroll
        for (int j = 0; j < 16; ++j) s += xv[j];
        xr[g][i] = s;
        __syncthreads();
        if (t < 32) {
            float v = 0.f;
            #pragma unroll
            for (int gg = 0; gg < 8; ++gg) v += xr[gg][t];
            xs[t] = v;
        }
        __syncthreads();
        const float* wbase = w_qkv + (size_t)(kc * 32) * QKVC + nb * 256 + t;
        float wv[32];
        #pragma unroll
        for (int i2 = 0; i2 < 32; ++i2)
            wv[i2] = wbase[(size_t)i2 * QKVC];
        float a0 = 0.f;
        #pragma unroll
        for (int i2 = 0; i2 < 32; ++i2)
            a0 += xs[i2] * wv[i2];
        spart[(size_t)(b * 16 + kc) * QKVC + nb * 256 + t] = a0;
    } else {
        int u = bid - 384;
        int nt = u >> 2;
        int kt = (u & 3) * 4 + (t >> 6);
        int lane = t & 63;
        int c = nt * 16 + (lane & 15);
        int kbase = kt * 32 + (lane >> 4) * 8;
        bf16x8 h, l;
        #pragma unroll
        for (int j = 0; j < 8; ++j) {
            float v = w_qkv[(size_t)(kbase + j) * QKVC + c];
            unsigned short hv = f2bf(v);
            h[j] = (short)hv;
            l[j] = (short)f2bf(v - bf2f(hv));
        }
        int idx = (nt * 16 + kt) * 64 + lane;
        hi[idx] = h;
        lo[idx] = l;
    }
}

// ---------------------------------------------------------------
// statsB: finalize qm/km/sv from spart, then rvec/cvec. grid (32, 2).
// spart chain fully unrolled (16 outstanding loads).
// ---------------------------------------------------------------
__global__ __launch_bounds__(256) void statsB(const float* __restrict__ spart,
                                              const float* __restrict__ w_qkv,
                                              float* __restrict__ sv,
                                              float* __restrict__ rvec,
                                              float* __restrict__ cvec) {
    int bh = blockIdx.x, cb = blockIdx.y;
    int b = bh >> 3, h = bh & 7;
    __shared__ float qm[64], km[64];
    int t = threadIdx.x;
    if (t < 192) {
        int which = t >> 6, d = t & 63;
        int col = which * 512 + h * 64 + d;
        float pv[16];
        #pragma unroll
        for (int kc = 0; kc < 16; ++kc)
            pv[kc] = spart[(size_t)(b * 16 + kc) * QKVC + col];
        float s = 0.f;
        #pragma unroll
        for (int kc = 0; kc < 16; ++kc) s += pv[kc];
        if (which == 0)      qm[d] = s * (1.0f / Nseq);
        else if (which == 1) km[d] = s * (1.0f / Nseq);
        else if (cb == 0)    sv[bh * 64 + d] = s;
    }
    __syncthreads();
    int c = cb * 256 + t;
    const float4* wr = (const float4*)(w_qkv + (size_t)c * QKVC + h * 64);
    const float4* wc = (const float4*)(w_qkv + (size_t)c * QKVC + 512 + h * 64);
    float r = 0.f, cv = 0.f;
    #pragma unroll
    for (int d4 = 0; d4 < 16; ++d4) {
        float4 w1 = wr[d4], w2 = wc[d4];
        float4 k1 = *(const float4*)&km[d4 * 4];
        float4 q1 = *(const float4*)&qm[d4 * 4];
        r  += w1.x * k1.x + w1.y * k1.y + w1.z * k1.z + w1.w * k1.w;
        cv += w2.x * q1.x + w2.y * q1.y + w2.z * q1.z + w2.w * q1.w;
    }
    rvec[(size_t)bh * Cdim + c] = r;
    cvec[(size_t)bh * Cdim + c] = cv;
}

// ---------------------------------------------------------------
// score4: single-pass rank-1 scores.  grid (4 b, 128 rc), 128 threads.
// ---------------------------------------------------------------
__global__ __launch_bounds__(128) void score4_kernel(const float* __restrict__ x,
                                                     const float* __restrict__ rvec,
                                                     const float* __restrict__ cvec,
                                                     float* __restrict__ rsc,
                                                     float* __restrict__ csc) {
    int b = blockIdx.x, rc = blockIdx.y;
    __shared__ float vs[16 * 8 * 68];     // 34.8 KB
    int t = threadIdx.x;
    int r = t >> 3, g = t & 7;

    const float4* xp = (const float4*)(x + ((size_t)b * Nseq + rc * 16 + r) * Cdim + g * 64);
    float4 xr[16];
    #pragma unroll
    for (int j4 = 0; j4 < 16; ++j4) xr[j4] = xp[j4];

    {
        const float4* rp = (const float4*)(rvec + (size_t)b * 8 * Cdim);
        const float4* cp = (const float4*)(cvec + (size_t)b * 8 * Cdim);
        for (int i = t; i < 16 * 128; i += 128) {
            int v = i >> 7, c4 = i & 127;
            float4 val = (v < 8) ? rp[v * 128 + c4] : cp[(v - 8) * 128 + c4];
            int gg = c4 >> 4, j4 = c4 & 15;
            *(float4*)&vs[(v * 8 + gg) * 68 + j4 * 4] = val;
        }
    }
    __syncthreads();

    float acc[16];
    #pragma unroll
    for (int v = 0; v < 16; ++v) acc[v] = 0.f;
    #pragma unroll
    for (int j4 = 0; j4 < 16; ++j4) {
        float4 xv = xr[j4];
        #pragma unroll
        for (int v = 0; v < 16; ++v) {
            float4 wv = *(const float4*)&vs[(v * 8 + g) * 68 + j4 * 4];
            acc[v] += xv.x * wv.x + xv.y * wv.y + xv.z * wv.z + xv.w * wv.w;
        }
    }
    #pragma unroll
    for (int v = 0; v < 16; ++v) {
        float s = acc[v];
        s += __shfl_xor(s, 1, 64);
        s += __shfl_xor(s, 2, 64);
        s += __shfl_xor(s, 4, 64);
        acc[v] = s;
    }
    if (g == 0) {
        int i = rc * 16 + r;
        #pragma unroll
        for (int v = 0; v < 8; ++v) {
            rsc[(size_t)(b * 8 + v) * Nseq + i] = acc[v] * 0.125f;
            csc[(size_t)(b * 8 + v) * Nseq + i] = acc[8 + v] * 0.125f;
        }
    }
}

// ---------------------------------------------------------------
// topk6: radix-select top-256, shfl scans + per-wave histograms.
// grid 64.  (unchanged round 12)
// ---------------------------------------------------------------
__global__ __launch_bounds__(256) void topk6(const float* __restrict__ rsc,
                                             const float* __restrict__ csc,
                                             int* __restrict__ ridx,
                                             int* __restrict__ cidx,
                                             int* __restrict__ rankmap) {
    int selid = blockIdx.x;
    int bh = selid >> 1, which = selid & 1;
    const float* sin = which ? (csc + (size_t)bh * Nseq) : (rsc + (size_t)bh * Nseq);
    __shared__ int hist[4][256];
    __shared__ int wsum[4];
    __shared__ int tieidx[2048];
    __shared__ int sh_D, sh_above, sh_tiecnt;
    int tid = threadIdx.x;
    int lane = tid & 63, wv = tid >> 6;

    unsigned k[8];
    #pragma unroll
    for (int j = 0; j < 8; ++j) {
        unsigned u = __float_as_uint(sin[j * 256 + tid]);
        k[j] = (u & 0x80000000u) ? ~u : (u | 0x80000000u);
    }

    unsigned pref = 0;
    int above = 0;
    for (int level = 3; level >= 0; --level) {
        hist[0][tid] = 0; hist[1][tid] = 0; hist[2][tid] = 0; hist[3][tid] = 0;
        __syncthreads();
        int sh = level * 8;
        #pragma unroll
        for (int j = 0; j < 8; ++j) {
            bool match = (level == 3) || ((k[j] >> (sh + 8)) == pref);
            if (match) atomicAdd(&hist[wv][(k[j] >> sh) & 255], 1);
        }
        __syncthreads();
        int h = hist[0][tid] + hist[1][tid] + hist[2][tid] + hist[3][tid];
        int v = h;
        #pragma unroll
        for (int off = 1; off < 64; off <<= 1) {
            int tt = __shfl_down(v, off, 64);
            if (lane + off < 64) v += tt;
        }
        if (lane == 0) wsum[wv] = v;
        __syncthreads();
        int add = 0;
        #pragma unroll
        for (int w = 0; w < 4; ++w) if (w > wv) add += wsum[w];
        v += add;
        int Sincl = v, Sexcl = v - h;
        if (above + Sexcl < TK && above + Sincl >= TK) {
            sh_D = tid;
            sh_above = above + Sexcl;
        }
        __syncthreads();
        pref = (pref << 8) | (unsigned)sh_D;
        above = sh_above;
        __syncthreads();
    }
    unsigned T = pref;
    int rem = TK - above;

    if (tid == 0) sh_tiecnt = 0;
    __syncthreads();
    int cnt = 0;
    #pragma unroll
    for (int j = 0; j < 8; ++j) {
        if (k[j] > T) ++cnt;
        if (k[j] == T) {
            int p = atomicAdd(&sh_tiecnt, 1);
            tieidx[p] = j * 256 + tid;
        }
    }
    int v = cnt;
    #pragma unroll
    for (int off = 1; off < 64; off <<= 1) {
        int tt = __shfl_up(v, off, 64);
        if (lane >= off) v += tt;
    }
    if (lane == 63) wsum[wv] = v;
    __syncthreads();
    int add = 0;
    #pragma unroll
    for (int w = 0; w < 4; ++w) if (w < wv) add += wsum[w];
    int base = v + add - cnt;
    int tc = sh_tiecnt;
    int* outp = which ? (cidx + bh * TK) : (ridx + bh * TK);
    #pragma unroll
    for (int j = 0; j < 8; ++j) {
        int i = j * 256 + tid;
        int r = -1;
        if (k[j] > T) {
            r = base++;
        } else if (k[j] == T) {
            int rk = 0;
            for (int t2 = 0; t2 < tc; ++t2) rk += (tieidx[t2] < i) ? 1 : 0;
            if (rk < rem) r = above + rk;
        }
        if (r >= 0) outp[r] = i;
        if (which == 0) rankmap[(size_t)bh * Nseq + i] = r;
    }
}

// ---------------------------------------------------------------
// selgemm4: barrier-free gather-GEMM, NI=4, 1-deep B prefetch.
// grid (4 mq, 3 part, 32 bh).  (unchanged round 12)
// ---------------------------------------------------------------
__global__ __launch_bounds__(256) void selgemm4(const float* __restrict__ x,
                                                const int* __restrict__ ridx,
                                                const int* __restrict__ cidx,
                                                const bf16x8* __restrict__ Bph,
                                                const bf16x8* __restrict__ Bpl,
                                                float* __restrict__ qsel,
                                                float* __restrict__ ksel,
                                                float* __restrict__ vsel) {
    int mq = blockIdx.x, part = blockIdx.y, bh = blockIdx.z;
    int b = bh >> 3, h = bh & 7;
    int tid = threadIdx.x;
    int wv = tid >> 6, lane = tid & 63;
    const int* idxp = (part == 0 ? ridx : cidx) + bh * TK + mq * 64 + wv * 16;
    int row = idxp[lane & 15];
    const float* ap = x + ((size_t)b * Nseq + row) * Cdim + (lane >> 4) * 8;
    size_t orow = (size_t)bh * TK + mq * 64 + wv * 16;
    int nt0 = (part == 0) ? (h * 4) : (part == 1 ? (32 + h * 4) : (64 + h * 4));
    float* outp = (part == 0) ? qsel : (part == 1 ? ksel : vsel);

    f32x4 acc[4];
    #pragma unroll
    for (int i = 0; i < 4; ++i) acc[i] = (f32x4){0.f, 0.f, 0.f, 0.f};

    bf16x8 bhc[4], blc[4];
    #pragma unroll
    for (int ni = 0; ni < 4; ++ni) {
        bhc[ni] = Bph[((size_t)(nt0 + ni) * 16 + 0) * 64 + lane];
        blc[ni] = Bpl[((size_t)(nt0 + ni) * 16 + 0) * 64 + lane];
    }
    float4 a0 = *(const float4*)ap;
    float4 a1 = *(const float4*)(ap + 4);
    #pragma unroll 2
    for (int kt = 0; kt < 16; ++kt) {
        float4 na0 = a0, na1 = a1;
        bf16x8 bhn[4], bln[4];
        if (kt < 15) {
            na0 = *(const float4*)(ap + (kt + 1) * 32);
            na1 = *(const float4*)(ap + (kt + 1) * 32 + 4);
            #pragma unroll
            for (int ni = 0; ni < 4; ++ni) {
                bhn[ni] = Bph[((size_t)(nt0 + ni) * 16 + (kt + 1)) * 64 + lane];
                bln[ni] = Bpl[((size_t)(nt0 + ni) * 16 + (kt + 1)) * 64 + lane];
            }
        }
        float vv[8] = {a0.x, a0.y, a0.z, a0.w, a1.x, a1.y, a1.z, a1.w};
        bf16x8 ah, al;
        #pragma unroll
        for (int j = 0; j < 8; ++j) {
            unsigned short hv = f2bf(vv[j]);
            ah[j] = (short)hv;
            al[j] = (short)f2bf(vv[j] - bf2f(hv));
        }
        #pragma unroll
        for (int ni = 0; ni < 4; ++ni) {
            acc[ni] = mfma16(ah, bhc[ni], acc[ni]);
            acc[ni] = mfma16(ah, blc[ni], acc[ni]);
            acc[ni] = mfma16(al, bhc[ni], acc[ni]);
        }
        if (kt < 15) {
            #pragma unroll
            for (int ni = 0; ni < 4; ++ni) { bhc[ni] = bhn[ni]; blc[ni] = bln[ni]; }
        }
        a0 = na0; a1 = na1;
    }
    int cl = lane & 15, rq = (lane >> 4) * 4;
    #pragma unroll
    for (int ni = 0; ni < 4; ++ni) {
        int csub = ni * 16 + cl;
        #pragma unroll
        for (int r = 0; r < 4; ++r)
            outp[(orow + rq + r) * 64 + csub] = acc[ni][r];
    }
}

// ---------------------------------------------------------------
// attn_fused4: grid (32 bh, 16 rblk).  PV unroll 16; QK unroll 16.
// ---------------------------------------------------------------
__global__ __launch_bounds__(256) void attn_fused4(const float* __restrict__ qsel,
                                                   const float* __restrict__ ksel,
                                                   const float* __restrict__ vsel,
                                                   const float* __restrict__ sv,
                                                   float* __restrict__ delta) {
    int bh = blockIdx.x;
    int rblk = blockIdx.y;
    __shared__ float Kt[64 * 256];       // 64 KB; E[16][256] aliases after QK
    __shared__ float Qs[16 * 64];        // 4 KB
    __shared__ float umS[16], izS[16];
    int tid = threadIdx.x;
    {
        int j = tid;
        const float4* kp4 = (const float4*)(ksel + ((size_t)bh * TK + j) * 64);
        float4 kv[16];
        #pragma unroll
        for (int d4 = 0; d4 < 16; ++d4) kv[d4] = kp4[d4];
        #pragma unroll
        for (int d4 = 0; d4 < 16; ++d4) {
            Kt[(d4 * 4 + 0) * 256 + j] = kv[d4].x;
            Kt[(d4 * 4 + 1) * 256 + j] = kv[d4].y;
            Kt[(d4 * 4 + 2) * 256 + j] = kv[d4].z;
            Kt[(d4 * 4 + 3) * 256 + j] = kv[d4].w;
        }
    }
    for (int idx = tid; idx < 16 * 64; idx += 256)
        Qs[idx] = qsel[((size_t)bh * TK + rblk * 16) * 64 + idx];
    __syncthreads();

    int wave = tid >> 6, lane = tid & 63;
    int iw0 = wave * 4;
    float e[4][4];
    #pragma unroll
    for (int r = 0; r < 4; ++r)
        #pragma unroll
        for (int t = 0; t < 4; ++t) e[r][t] = 0.f;
    #pragma unroll 16
    for (int d = 0; d < 64; ++d) {
        float4 kv = *(const float4*)&Kt[d * 256 + 4 * lane];
        #pragma unroll
        for (int r = 0; r < 4; ++r) {
            float qd = Qs[(iw0 + r) * 64 + d];
            e[r][0] += qd * kv.x; e[r][1] += qd * kv.y;
            e[r][2] += qd * kv.z; e[r][3] += qd * kv.w;
        }
    }
    #pragma unroll
    for (int r = 0; r < 4; ++r) {
        float s0 = e[r][0] * 0.125f, s1 = e[r][1] * 0.125f;
        float s2 = e[r][2] * 0.125f, s3 = e[r][3] * 0.125f;
        float mx = fmaxf(fmaxf(s0, s1), fmaxf(s2, s3));
        #pragma unroll
        for (int off = 32; off; off >>= 1) mx = fmaxf(mx, __shfl_xor(mx, off, 64));
        mx = fmaxf(mx, 0.0f);
        float e0 = __expf(s0 - mx), e1 = __expf(s1 - mx);
        float e2 = __expf(s2 - mx), e3 = __expf(s3 - mx);
        float zs = e0 + e1 + e2 + e3;
        #pragma unroll
        for (int off = 32; off; off >>= 1) zs += __shfl_xor(zs, off, 64);
        if (lane == 0) {
            float em = __expf(-mx);
            umS[iw0 + r] = em;
            izS[iw0 + r] = 1.0f / ((float)(Nseq - TK) * em + zs);
        }
        e[r][0] = e0; e[r][1] = e1; e[r][2] = e2; e[r][3] = e3;
    }
    __syncthreads();
    float* E = Kt;
    #pragma unroll
    for (int r = 0; r < 4; ++r)
        *(float4*)&E[(iw0 + r) * 256 + 4 * lane] = (float4){e[r][0], e[r][1], e[r][2], e[r][3]};
    __syncthreads();

    const float* vbase = vsel + (size_t)bh * TK * 64 + lane;
    float ssel = 0.f;
    float acc[4];
    #pragma unroll
    for (int r = 0; r < 4; ++r) acc[r] = 0.f;
    #pragma unroll 16
    for (int j = 0; j < TK; ++j) {
        float v = vbase[j * 64];
        ssel += v;
        #pragma unroll
        for (int r = 0; r < 4; ++r)
            acc[r] += E[(iw0 + r) * 256 + j] * v;
    }
    float svd = sv[bh * 64 + lane];
    float sadj = svd - ssel;
    float uval = svd * (1.0f / Nseq);
    #pragma unroll
    for (int r = 0; r < 4; ++r) {
        int i = rblk * 16 + iw0 + r;
        float outv = (umS[iw0 + r] * sadj + acc[r]) * izS[iw0 + r];
        delta[((size_t)bh * TK + i) * 64 + lane] = outv - uval;
    }
}

// ---------------------------------------------------------------
// deltamm_ub: 64-row tiles; register-staged LDS fills (all loads
// issued before writes); ubase unroll 8.
// ---------------------------------------------------------------
__global__ __launch_bounds__(256) void deltamm_ub(const float* __restrict__ delta,
                                                  const float* __restrict__ w_out,
                                                  const float* __restrict__ b_out,
                                                  const float* __restrict__ sv,
                                                  float* __restrict__ deltaout,
                                                  float* __restrict__ ubase) {
    int bid = blockIdx.x;
    int tid = threadIdx.x;
    if (bid < 512) {
        int bh = bid >> 4, sub = bid & 15;
        int rh = sub >> 2, ct = sub & 3;
        int h = bh & 7;
        __shared__ float As[64][65];
        __shared__ float Ws[64][132];
        {
            float av[16];
            #pragma unroll
            for (int it = 0; it < 16; ++it) {
                int idx = tid + it * 256;
                int row = idx >> 6, k = idx & 63;
                av[it] = delta[((size_t)bh * TK + rh * 64 + row) * 64 + k];
            }
            float wv[32];
            #pragma unroll
            for (int it = 0; it < 32; ++it) {
                int idx = tid + it * 256;
                int k = idx >> 7, c = idx & 127;
                wv[it] = w_out[(size_t)(h * 64 + k) * 512 + ct * 128 + c];
            }
            #pragma unroll
            for (int it = 0; it < 16; ++it) {
                int idx = tid + it * 256;
                As[idx >> 6][idx & 63] = av[it];
            }
            #pragma unroll
            for (int it = 0; it < 32; ++it) {
                int idx = tid + it * 256;
                Ws[idx >> 7][idx & 127] = wv[it];
            }
        }
        __syncthreads();
        int tx = tid & 15, ty = tid >> 4;
        float acc[4][8];
        #pragma unroll
        for (int r = 0; r < 4; ++r)
            #pragma unroll
            for (int c = 0; c < 8; ++c) acc[r][c] = 0.f;
        for (int k = 0; k < 64; ++k) {
            float a[4], bv[8];
            #pragma unroll
            for (int r = 0; r < 4; ++r) a[r] = As[ty * 4 + r][k];
            #pragma unroll
            for (int cc = 0; cc < 4; ++cc) {
                bv[cc]     = Ws[k][tx * 4 + cc];
                bv[4 + cc] = Ws[k][64 + tx * 4 + cc];
            }
            #pragma unroll
            for (int r = 0; r < 4; ++r)
                #pragma unroll
                for (int c = 0; c < 8; ++c) acc[r][c] += a[r] * bv[c];
        }
        #pragma unroll
        for (int r = 0; r < 4; ++r) {
            size_t ro = ((size_t)bh * TK + rh * 64 + ty * 4 + r) * 512 + ct * 128;
            #pragma unroll
            for (int cc = 0; cc < 4; ++cc) {
                deltaout[ro + tx * 4 + cc]      = acc[r][cc];
                deltaout[ro + 64 + tx * 4 + cc] = acc[r][4 + cc];
            }
        }
    } else {
        int r2 = bid - 512;
        int b = r2 >> 3;
        int c0 = (r2 & 7) * 64;
        int c = tid & 63, kg = tid >> 6;
        float s = 0.f;
        #pragma unroll 8
        for (int k = kg * 128; k < kg * 128 + 128; ++k) {
            float hu = sv[(b * 8 + (k >> 6)) * 64 + (k & 63)] * (1.0f / Nseq);
            s += hu * w_out[(size_t)k * 512 + c0 + c];
        }
        __shared__ float red[4][64];
        red[kg][c] = s;
        __syncthreads();
        if (tid < 64)
            ubase[b * 512 + c0 + c] = red[0][c] + red[1][c] + red[2][c] + red[3][c] + b_out[c0 + c];
    }
}

// ---------------------------------------------------------------
// compose2: rankmap preloaded into registers before gathers.
// ---------------------------------------------------------------
__global__ __launch_bounds__(256) void compose2(const float* __restrict__ ubase,
                                                const int* __restrict__ rankmap,
                                                const float* __restrict__ deltaout,
                                                float* __restrict__ out) {
    int r0 = blockIdx.x * 4;
    int b = r0 >> 11;
    int tid = threadIdx.x;
    float u0 = ubase[b * 512 + tid];
    float u1 = ubase[b * 512 + 256 + tid];
    for (int rr = 0; rr < 4; ++rr) {
        int i = (r0 + rr) & 2047;
        int rk[8];
        #pragma unroll
        for (int h = 0; h < 8; ++h)
            rk[h] = rankmap[(size_t)(b * 8 + h) * Nseq + i];
        float a0 = u0, a1 = u1;
        #pragma unroll
        for (int h = 0; h < 8; ++h) {
            if (rk[h] >= 0) {
                const float* dp = deltaout + ((size_t)(b * 8 + h) * TK + rk[h]) * 512;
                a0 += dp[tid];
                a1 += dp[256 + tid];
            }
        }
        float* op = out + ((size_t)b * Nseq + i) * 512;
        op[tid] = a0;
        op[256 + tid] = a1;
    }
}

extern "C" void kernel_launch(void* const* d_in, const int* in_sizes, int n_in,
                              void* d_out, int out_size, void* d_ws, size_t ws_size,
                              hipStream_t stream) {
    const float* x     = (const float*)d_in[0];
    const float* w_qkv = (const float*)d_in[1];
    const float* w_out = (const float*)d_in[2];
    const float* b_out = (const float*)d_in[3];
    float* out = (float*)d_out;

    float* ws = (float*)d_ws;
    float* xpart   = ws;                            // 262144 f
    float* spart   = xpart + 262144;                // 98304 f
    float* sv      = spart + 98304;                 // 2048 f
    float* rvec    = sv + 2048;                     // 16384 f
    float* cvec    = rvec + 16384;
    float* rsc     = cvec + 16384;                  // 65536 f
    float* csc     = rsc + 65536;
    int*   ridx    = (int*)(csc + 65536);           // 8192 i
    int*   cidx    = ridx + 8192;
    int*   rankmap = cidx + 8192;                   // 65536 i
    float* ubase   = (float*)(rankmap + 65536);     // 2048 f
    bf16x8* Bp_hi  = (bf16x8*)(ubase + 2048);       // 393216 f
    bf16x8* Bp_lo  = (bf16x8*)((float*)Bp_hi + 393216);
    float* qsel    = (float*)Bp_lo + 393216;        // 524288 f
    float* ksel    = qsel + 524288;
    float* vsel    = ksel + 524288;
    float* delta   = vsel + 524288;                 // 524288 f
    float* deltaout = delta + 524288;               // 4194304 f

    // 1. x column partial sums (deep load ILP)
    xprep<<<512, 256, 0, stream>>>(x, xpart);
    // 2. partial stats GEMM + W fragment packing (deep load ILP)
    statsAW<<<768, 256, 0, stream>>>(xpart, w_qkv, spart, Bp_hi, Bp_lo);
    // 3. finalize qm/km/sv + folded score vectors (deep load ILP)
    statsB<<<dim3(BH, 2), 256, 0, stream>>>(spart, w_qkv, sv, rvec, cvec);
    // 4. rank-1 scores, single pass over x
    score4_kernel<<<dim3(Bsz, 128), 128, 0, stream>>>(x, rvec, cvec, rsc, csc);
    // 5. top-256 + rankmap via radix-select
    topk6<<<BH * 2, 256, 0, stream>>>(rsc, csc, ridx, cidx, rankmap);
    // 6. barrier-free gather-GEMM (B prefetch)
    selgemm4<<<dim3(4, 3, BH), 256, 0, stream>>>(x, ridx, cidx, Bp_hi, Bp_lo, qsel, ksel, vsel);
    // 7. fused attention (deep-ILP QK+PV) -> compact delta
    attn_fused4<<<dim3(BH, 16), 256, 0, stream>>>(qsel, ksel, vsel, sv, delta);
    // 8. delta @ w_out (register-staged LDS fills) + uniform base rows
    deltamm_ub<<<544, 256, 0, stream>>>(delta, w_out, b_out, sv, deltaout, ubase);
    // 9. compose final output
    compose2<<<Bsz * Nseq / 4, 256, 0, stream>>>(ubase, rankmap, deltaout, out);
}